// Round 12
// baseline (366.776 us; speedup 1.0000x reference)
//
#include <hip/hip_runtime.h>
#include <hip/hip_bf16.h>

typedef __attribute__((ext_vector_type(8))) short short8;
typedef __attribute__((ext_vector_type(4))) float floatx4;
typedef __attribute__((ext_vector_type(4))) unsigned int uintx4;

#define D_MODEL 1024
#define T_SEQ   2048
#define N_HEAD  16
#define NEG_BIG (-1e30f)
#define LDSP 40 // fallback-gemm pitch
#define VP 72   // V-tile pitch: 144B rows, 16B-aligned -> true ds_read_b128
#define PP 72   // P-tile pitch

static __device__ __forceinline__ float bf2f(ushort u) {
  unsigned int x = ((unsigned int)u) << 16;
  return __builtin_bit_cast(float, x);
}
static __device__ __forceinline__ ushort san(ushort u) {
  return ((u & 0x7F80u) == 0x7F80u) ? (ushort)0 : u;
}
static __device__ __forceinline__ float bf2f_s(ushort u) { return bf2f(san(u)); }
static __device__ __forceinline__ ushort f2bf(float f) {
  unsigned int x = __builtin_bit_cast(unsigned int, f);
  x += 0x7FFFu + ((x >> 16) & 1u);
  return (ushort)(x >> 16);
}
static __device__ __forceinline__ float ext_ld(const void* p, size_t i, int isbf) {
  return isbf ? bf2f_s(((const ushort*)p)[i]) : ((const float*)p)[i];
}
// async global->LDS DMA, 16 B/lane; LDS dest = wave-uniform base + lane*16
static __device__ __forceinline__ void gload16(const void* g, void* l) {
  __builtin_amdgcn_global_load_lds(
      (const __attribute__((address_space(1))) void*)g,
      (__attribute__((address_space(3))) void*)l, 16, 0, 0);
}
// block barrier WITHOUT vmcnt drain: LDS writes visible (lgkmcnt), but
// register-destined global prefetches stay in flight across the barrier
// (compiler still inserts vmcnt(N) before each use). sched_barrier pins
// against hipcc hoisting past inline-asm waitcnt (rule #18).
static __device__ __forceinline__ void barrier_lds_only() {
  asm volatile("s_waitcnt lgkmcnt(0)" ::: "memory");
  __builtin_amdgcn_s_barrier();
  __builtin_amdgcn_sched_barrier(0);
}

// dtype probe: low ushort of dword -> bf16 data has exp in [0x60,0x8F] ~100%
__global__ void detect_dtype(const ushort* x, uint* flag) {
  int tid = threadIdx.x;
  int cnt = 0;
  for (int j = 0; j < 16; j++) {
    ushort u = x[2 * (tid * 16 + j)];
    int e = (u >> 7) & 0xFF;
    if (e >= 0x60 && e <= 0x8F) cnt++;
  }
  for (int d = 32; d; d >>= 1) cnt += __shfl_xor(cnt, d, 64);
  __shared__ int c[4];
  if ((tid & 63) == 0) c[tid >> 6] = cnt;
  __syncthreads();
  if (tid == 0) flag[0] = (c[0] + c[1] + c[2] + c[3] >= 2048) ? 1u : 0u;
}

// prep_all: ALL weight convert+transpose (blocks 0..8191) + LN1 (8192..12287)
__global__ __launch_bounds__(256) void prep_all(
    const void* __restrict__ Wq, const void* __restrict__ Wk,
    const void* __restrict__ Wv, const void* __restrict__ Wo,
    const void* __restrict__ W1, const void* __restrict__ W2,
    ushort* __restrict__ oq, ushort* __restrict__ ok, ushort* __restrict__ ov,
    ushort* __restrict__ oo, ushort* __restrict__ o1, ushort* __restrict__ o2,
    const void* __restrict__ x, const void* __restrict__ ln_g,
    const void* __restrict__ ln_b, ushort* __restrict__ ln_out,
    const uint* __restrict__ flagp) {
  int isbf = (int)*flagp;
  int id = blockIdx.x;
  int tid = threadIdx.x;

  if (id >= 8192) {
    // ---- LN1 row (ext input: dtype follows flag) ----
    int row = id - 8192;
    size_t ro = (size_t)row * D_MODEL;
    float v[4], gv[4], bv[4];
    if (!isbf) {
      floatx4 xv = *((const floatx4*)((const float*)x + ro) + tid);
#pragma unroll
      for (int i = 0; i < 4; i++) v[i] = xv[i];
    } else {
#pragma unroll
      for (int i = 0; i < 4; i++) v[i] = bf2f_s(((const ushort*)x)[ro + tid * 4 + i]);
    }
    float s = 0.f, sq = 0.f;
#pragma unroll
    for (int i = 0; i < 4; i++) { s += v[i]; sq += v[i] * v[i]; }
#pragma unroll
    for (int d = 32; d; d >>= 1) {
      s += __shfl_xor(s, d, 64);
      sq += __shfl_xor(sq, d, 64);
    }
    __shared__ float red[8];
    int wave = tid >> 6, lane = tid & 63;
    if (lane == 0) { red[wave] = s; red[4 + wave] = sq; }
    __syncthreads();
    s = red[0] + red[1] + red[2] + red[3];
    sq = red[4] + red[5] + red[6] + red[7];
    float mu = s * (1.0f / D_MODEL);
    float var = sq * (1.0f / D_MODEL) - mu * mu;
    float rs = rsqrtf(fmaxf(var, 0.f) + 1e-5f);
    if (!isbf) {
      floatx4 g4 = *((const floatx4*)ln_g + tid);
      floatx4 b4 = *((const floatx4*)ln_b + tid);
#pragma unroll
      for (int i = 0; i < 4; i++) { gv[i] = g4[i]; bv[i] = b4[i]; }
    } else {
#pragma unroll
      for (int i = 0; i < 4; i++) {
        gv[i] = bf2f_s(((const ushort*)ln_g)[tid * 4 + i]);
        bv[i] = bf2f_s(((const ushort*)ln_b)[tid * 4 + i]);
      }
    }
    ushort o4[4];
#pragma unroll
    for (int i = 0; i < 4; i++) o4[i] = f2bf((v[i] - mu) * rs * gv[i] + bv[i]);
    *(uint2*)(ln_out + ro + tid * 4) = *(uint2*)o4;
    return;
  }

  // ---- weight convert+transpose tile ----
  const void* in;
  ushort* out;
  int R, C, local;
  if (id < 4096) {
    int w = id >> 10;
    local = id & 1023;
    R = 1024; C = 1024;
    in  = (w == 0) ? Wq : (w == 1) ? Wk : (w == 2) ? Wv : Wo;
    out = (w == 0) ? oq : (w == 1) ? ok : (w == 2) ? ov : oo;
  } else if (id < 6144) {
    local = id - 4096; R = 1024; C = 2048; in = W1; out = o1;
  } else {
    local = id - 6144; R = 2048; C = 1024; in = W2; out = o2;
  }
  int cb = C >> 5;
  int c0 = (local % cb) * 32, r0 = (local / cb) * 32;
  __shared__ float t[32][33];
  int tx = tid & 31, ty = tid >> 5;
  for (int i = ty; i < 32; i += 8)
    t[i][tx] = ext_ld(in, (size_t)(r0 + i) * C + c0 + tx, isbf);
  __syncthreads();
  for (int i = ty; i < 32; i += 8)
    out[(size_t)(c0 + i) * R + r0 + tx] = f2bf(t[tx][i]);
}

// ---------------- LayerNorm -> bf16 (LN2 only now) ----------------
__global__ __launch_bounds__(256) void ln_kernel(
    const void* __restrict__ x, const void* __restrict__ g,
    const void* __restrict__ bb, ushort* __restrict__ out,
    int ext, const uint* __restrict__ flagp) {
  int wbf = (int)*flagp;
  int xbf = ext ? wbf : 1;
  int row = blockIdx.x, tid = threadIdx.x;
  size_t ro = (size_t)row * D_MODEL;
  float v[4], gv[4], bv[4];
  if (!xbf) {
    floatx4 xv = *((const floatx4*)((const float*)x + ro) + tid);
#pragma unroll
    for (int i = 0; i < 4; i++) v[i] = xv[i];
  } else {
#pragma unroll
    for (int i = 0; i < 4; i++) v[i] = bf2f_s(((const ushort*)x)[ro + tid * 4 + i]);
  }
  float s = 0.f, sq = 0.f;
#pragma unroll
  for (int i = 0; i < 4; i++) { s += v[i]; sq += v[i] * v[i]; }
#pragma unroll
  for (int d = 32; d; d >>= 1) {
    s += __shfl_xor(s, d, 64);
    sq += __shfl_xor(sq, d, 64);
  }
  __shared__ float red[8];
  int wave = tid >> 6, lane = tid & 63;
  if (lane == 0) { red[wave] = s; red[4 + wave] = sq; }
  __syncthreads();
  s = red[0] + red[1] + red[2] + red[3];
  sq = red[4] + red[5] + red[6] + red[7];
  float mu = s * (1.0f / D_MODEL);
  float var = sq * (1.0f / D_MODEL) - mu * mu;
  float rs = rsqrtf(fmaxf(var, 0.f) + 1e-5f);
  if (!wbf) {
    floatx4 g4 = *((const floatx4*)g + tid);
    floatx4 b4 = *((const floatx4*)bb + tid);
#pragma unroll
    for (int i = 0; i < 4; i++) { gv[i] = g4[i]; bv[i] = b4[i]; }
  } else {
#pragma unroll
    for (int i = 0; i < 4; i++) {
      gv[i] = bf2f_s(((const ushort*)g)[tid * 4 + i]);
      bv[i] = bf2f_s(((const ushort*)bb)[tid * 4 + i]);
    }
  }
  ushort o4[4];
#pragma unroll
  for (int i = 0; i < 4; i++) o4[i] = f2bf((v[i] - mu) * rs * gv[i] + bv[i]);
  *(uint2*)(out + ro + tid * 4) = *(uint2*)o4;
}

// ---------------- fast GEMM: C = A[M,K] @ Bt[N,K]^T, both bf16 --------------
// EPI: 0 plain bf16 | 1 +res(ext) bf16 | 2 +bias(ext)+GELU bf16 |
//      5 +bias(ext)+res(bf16) -> store FINAL dtype
// NT: QKV/FF1=128 (density wins at >=2 blocks/CU, r10); Wo/FF2=64 (r4: these
// would be 1/CU at NT=128). KSTEP=32 (r8's 64 regressed, m132-class).
template <int EPI, int SPLIT, int NT, int KSTEP>
__global__ __launch_bounds__(256) void gemm_tt(
    const ushort* __restrict__ A, int lda,
    const ushort* __restrict__ Bt, int ldbt,
    void* __restrict__ C0v, ushort* __restrict__ C1, ushort* __restrict__ C2,
    int ldc,
    const void* __restrict__ bias, size_t biasoff,
    const void* __restrict__ res, int ldr,
    int M, int K, const uint* __restrict__ flagp) {
  __shared__ __align__(16) ushort As[128 * KSTEP];
  __shared__ __align__(16) ushort Bs[NT * KSTEP];
  int isbf = (int)*flagp;
  int tid = threadIdx.x;
  int wave = tid >> 6, lane = tid & 63, lm = lane & 15, quad = lane >> 4;
  int m0 = blockIdx.x * 128, n0 = blockIdx.y * NT;
  constexpr int MR = (NT == 128) ? 4 : 2;
  constexpr int RPW = 512 / KSTEP;   // rows per wave-DMA
  constexpr int RPC = 4 * RPW;       // rows per gload16 call (4 waves)
  constexpr int LPR = KSTEP / 8;     // lanes per row
  int wm = (NT == 128) ? (wave >> 1) * 64 : wave * 32;
  int wn = (NT == 128) ? (wave & 1) * 64 : 0;
  floatx4 acc[MR][4] = {};
  int srl = lane / LPR;
  int scl = (lane % LPR) * 8;

  for (int kk = 0; kk < K; kk += KSTEP) {
#pragma unroll
    for (int i = 0; i < 128 / RPC; i++)
      gload16(A + (size_t)(m0 + i * RPC + wave * RPW + srl) * lda + kk + scl,
              &As[(i * RPC + wave * RPW) * KSTEP]);
#pragma unroll
    for (int i = 0; i < NT / RPC; i++)
      gload16(Bt + (size_t)(n0 + i * RPC + wave * RPW + srl) * ldbt + kk + scl,
              &Bs[(i * RPC + wave * RPW) * KSTEP]);
    __syncthreads();
#pragma unroll
    for (int kk2 = 0; kk2 < KSTEP; kk2 += 32) {
      short8 af[MR], bf[4];
#pragma unroll
      for (int i = 0; i < MR; i++)
        af[i] = *(const short8*)&As[(wm + i * 16 + lm) * KSTEP + kk2 + quad * 8];
#pragma unroll
      for (int i = 0; i < 4; i++)
        bf[i] = *(const short8*)&Bs[(wn + i * 16 + lm) * KSTEP + kk2 + quad * 8];
#pragma unroll
      for (int mi = 0; mi < MR; mi++)
#pragma unroll
        for (int ni = 0; ni < 4; ni++)
          acc[mi][ni] = __builtin_amdgcn_mfma_f32_16x16x32_bf16(
              af[mi], bf[ni], acc[mi][ni], 0, 0, 0);
    }
    __syncthreads();
  }

  ushort* Cseg = (ushort*)C0v;
  int colbase = n0;
  if (SPLIT) {
    int seg = n0 >> 10;
    Cseg = (seg == 0) ? (ushort*)C0v : (seg == 1 ? C1 : C2);
    colbase = n0 & 1023;
  }
#pragma unroll
  for (int mi = 0; mi < MR; mi++) {
#pragma unroll
    for (int ni = 0; ni < 4; ni++) {
      int col = colbase + wn + ni * 16 + lm;
#pragma unroll
      for (int r = 0; r < 4; r++) {
        int row = m0 + wm + mi * 16 + quad * 4 + r;
        size_t ci = (size_t)row * ldc + col;
        float v = acc[mi][ni][r];
        if (EPI == 2 || EPI == 5) v += ext_ld(bias, biasoff + col, isbf);
        if (EPI == 1) v += ext_ld(res, (size_t)row * ldr + col, isbf);
        if (EPI == 5) v += bf2f(((const ushort*)res)[(size_t)row * ldr + col]);
        if (EPI == 2) v = 0.5f * v * (1.0f + erff(v * 0.70710678118654752f));
        if (EPI == 5 && !isbf) ((float*)C0v)[ci] = v;
        else                   Cseg[ci] = f2bf(v);
      }
    }
  }
}

// ---------------- fallback GEMM: B in [K,N] external dtype ------------------
template <int EPI, int FINAL>
__global__ __launch_bounds__(256) void gemm_kn(
    const ushort* __restrict__ A, int lda,
    const void* __restrict__ B, int ldb, size_t boff,
    void* __restrict__ C, int ldc,
    const void* __restrict__ bias, size_t biasoff,
    const void* __restrict__ res, int ldr,
    int M, int K, const uint* __restrict__ flagp) {
  __shared__ __align__(16) ushort As[128 * LDSP];
  __shared__ __align__(16) ushort Bs[128 * LDSP];
  int isbf = (int)*flagp;
  int tid = threadIdx.x;
  int wave = tid >> 6, lane = tid & 63, lm = lane & 15, quad = lane >> 4;
  int m0 = blockIdx.x * 128, n0 = blockIdx.y * 128;
  int wm = (wave >> 1) * 64, wn = (wave & 1) * 64;
  floatx4 acc[4][4] = {};
  int sr = tid >> 2;
  int sc = (tid & 3) * 8;
  int bk = tid >> 4;
  int bn8 = (tid & 15) * 8;

  for (int kk = 0; kk < K; kk += 32) {
    uintx4 va0 = *(const uintx4*)(A + (size_t)(m0 + sr) * lda + kk + sc);
    uintx4 va1 = *(const uintx4*)(A + (size_t)(m0 + sr + 64) * lda + kk + sc);
    *(uintx4*)&As[sr * LDSP + sc] = va0;
    *(uintx4*)&As[(sr + 64) * LDSP + sc] = va1;
    if (isbf) {
      const ushort* Bu = (const ushort*)B;
#pragma unroll
      for (int p = 0; p < 2; p++) {
        int krow = bk + p * 16;
        uintx4 raw = *(const uintx4*)(Bu + boff + (size_t)(kk + krow) * ldb + n0 + bn8);
        ushort tmp[8] __attribute__((aligned(16)));
        *(uintx4*)tmp = raw;
#pragma unroll
        for (int i = 0; i < 8; i++) Bs[(bn8 + i) * LDSP + krow] = san(tmp[i]);
      }
    } else {
      const float* Bf = (const float*)B;
#pragma unroll
      for (int p = 0; p < 2; p++) {
        int krow = bk + p * 16;
        const float* src = Bf + boff + (size_t)(kk + krow) * ldb + n0 + bn8;
        floatx4 f0 = *(const floatx4*)src;
        floatx4 f1 = *(const floatx4*)(src + 4);
#pragma unroll
        for (int i = 0; i < 4; i++) {
          Bs[(bn8 + i) * LDSP + krow] = f2bf(f0[i]);
          Bs[(bn8 + 4 + i) * LDSP + krow] = f2bf(f1[i]);
        }
      }
    }
    __syncthreads();
    short8 af[4], bf[4];
#pragma unroll
    for (int i = 0; i < 4; i++)
      af[i] = *(const short8*)&As[(wm + i * 16 + lm) * LDSP + quad * 8];
#pragma unroll
    for (int i = 0; i < 4; i++)
      bf[i] = *(const short8*)&Bs[(wn + i * 16 + lm) * LDSP + quad * 8];
#pragma unroll
    for (int mi = 0; mi < 4; mi++)
#pragma unroll
      for (int ni = 0; ni < 4; ni++)
        acc[mi][ni] = __builtin_amdgcn_mfma_f32_16x16x32_bf16(
            af[mi], bf[ni], acc[mi][ni], 0, 0, 0);
    __syncthreads();
  }

#pragma unroll
  for (int mi = 0; mi < 4; mi++) {
#pragma unroll
    for (int ni = 0; ni < 4; ni++) {
      int col = n0 + wn + ni * 16 + lm;
#pragma unroll
      for (int r = 0; r < 4; r++) {
        int row = m0 + wm + mi * 16 + quad * 4 + r;
        size_t ci = (size_t)row * ldc + col;
        float v = acc[mi][ni][r];
        if (EPI == 4)
          v += (FINAL && !isbf) ? ((const float*)C)[ci] : bf2f(((const ushort*)C)[ci]);
        if (EPI == 2 || EPI == 4) v += ext_ld(bias, biasoff + col, isbf);
        if (EPI == 1) v += ext_ld(res, (size_t)row * ldr + col, isbf);
        if (EPI == 4) v += bf2f(((const ushort*)res)[(size_t)row * ldr + col]);
        if (EPI == 2) v = 0.5f * v * (1.0f + erff(v * 0.70710678118654752f));
        if (FINAL && !isbf) ((float*)C)[ci] = v;
        else                ((ushort*)C)[ci] = f2bf(v);
      }
    }
  }
}

// ---------------- causal flash attention -----------------------------------
// r7 structure (uniform pairing, swapped softmax, single Vst, 2 barriers per
// tile) with ONE change: barriers are {lgkmcnt(0); s_barrier} instead of
// __syncthreads -- __syncthreads' implicit vmcnt(0) was draining the
// register-destined V/K prefetches at BOTH barriers every iteration,
// exposing L2/HBM latency twice per tile. LDS hazards (Vst/P scatter+reads)
// are lgkm-counted and still drained; vmem loads float to their use point
// where the compiler inserts vmcnt(N).
__global__ __launch_bounds__(256) void attn_kernel(
    const ushort* __restrict__ q, const ushort* __restrict__ k,
    const ushort* __restrict__ v, ushort* __restrict__ ctx) {
  int tid = threadIdx.x, wave = tid >> 6, lane = tid & 63;
  int lm = lane & 15, quad = lane >> 4;
  int bx = blockIdx.x, h = blockIdx.y, b = blockIdx.z;
  size_t base = (size_t)b * T_SEQ * D_MODEL + h * 64;

  __shared__ __align__(16) ushort Vst[64 * VP];      // [hd][key]
  __shared__ __align__(16) ushort PlAll[4][16 * PP]; // per-wave P
  ushort* Pl = PlAll[wave];

  int vr_r = tid & 63, vcg = (tid >> 6) * 16;
  const ushort* vrow = v + base + vcg;

#pragma unroll
  for (int qsel = 0; qsel < 2; ++qsel) {
    int qt = qsel ? (31 - bx) : bx;
    int qw = qt * 64 + wave * 16;

    short8 aq0 = *(const short8*)&q[base + (size_t)(qw + lm) * D_MODEL + quad * 8];
    short8 aq1 = *(const short8*)&q[base + (size_t)(qw + lm) * D_MODEL + 32 + quad * 8];

    floatx4 O[4] = {};
    float mrq = NEG_BIG, lrq = 0.f;  // running max/denom for query qw+lm

    int ntiles = qt + 1;

    // prefetch tile 0
    uintx4 vv0 = *(const uintx4*)(vrow + (size_t)vr_r * D_MODEL);
    uintx4 vv1 = *(const uintx4*)(vrow + (size_t)vr_r * D_MODEL + 8);
    short8 kfa[4], kfb[4];
#pragma unroll
    for (int g = 0; g < 4; g++) {
      const ushort* kr = &k[base + (size_t)(g * 16 + lm) * D_MODEL + quad * 8];
      kfa[g] = *(const short8*)kr;
      kfb[g] = *(const short8*)(kr + 32);
    }

    for (int kt = 0; kt < ntiles; ++kt) {
      int k0 = kt * 64;
      // scatter prefetched V into shared Vst (all 256 threads)
      {
        ushort t0[8] __attribute__((aligned(16)));
        ushort t1[8] __attribute__((aligned(16)));
        *(uintx4*)t0 = vv0;
        *(uintx4*)t1 = vv1;
#pragma unroll
        for (int i = 0; i < 8; i++) {
          Vst[(vcg + i) * VP + vr_r] = t0[i];
          Vst[(vcg + 8 + i) * VP + vr_r] = t1[i];
        }
      }
      // QK^T SWAPPED: sc[g] = S^T[key=g*16+quad*4+r][query=lm]
      floatx4 sc[4];
#pragma unroll
      for (int g = 0; g < 4; g++) {
        floatx4 z = {};
        sc[g] = __builtin_amdgcn_mfma_f32_16x16x32_bf16(kfa[g], aq0, z, 0, 0, 0);
        sc[g] = __builtin_amdgcn_mfma_f32_16x16x32_bf16(kfb[g], aq1, sc[g], 0, 0, 0);
      }
      // issue prefetch for next tile (consumed after 2 barriers; stays in
      // flight across the LDS-only barriers)
      int k0n = (kt + 1 < ntiles) ? k0 + 64 : k0;
      uintx4 nv0 = *(const uintx4*)(vrow + (size_t)(k0n + vr_r) * D_MODEL);
      uintx4 nv1 = *(const uintx4*)(vrow + (size_t)(k0n + vr_r) * D_MODEL + 8);
      short8 nka[4], nkb[4];
#pragma unroll
      for (int g = 0; g < 4; g++) {
        const ushort* kr = &k[base + (size_t)(k0n + g * 16 + lm) * D_MODEL + quad * 8];
        nka[g] = *(const short8*)kr;
        nkb[g] = *(const short8*)(kr + 32);
      }
      // online softmax: lane owns query qw+lm, 16 keys in-lane
      bool full = (k0 + 63 <= qw);
      int qrow = qw + lm;
      float a[16];
#pragma unroll
      for (int g = 0; g < 4; g++)
#pragma unroll
        for (int r = 0; r < 4; r++) {
          float s = sc[g][r] * 0.125f;
          if (!full && (k0 + g * 16 + quad * 4 + r > qrow)) s = NEG_BIG;
          a[g * 4 + r] = s;
        }
      float m0 = fmaxf(fmaxf(a[0], a[1]), fmaxf(a[2], a[3]));
      float m1 = fmaxf(fmaxf(a[4], a[5]), fmaxf(a[6], a[7]));
      float m2 = fmaxf(fmaxf(a[8], a[9]), fmaxf(a[10], a[11]));
      float m3 = fmaxf(fmaxf(a[12], a[13]), fmaxf(a[14], a[15]));
      float tm = fmaxf(fmaxf(m0, m1), fmaxf(m2, m3));
      tm = fmaxf(tm, __shfl_xor(tm, 16, 64));
      tm = fmaxf(tm, __shfl_xor(tm, 32, 64));
      float mn = fmaxf(mrq, tm);
      float alpha = __expf(mrq - mn);
      float rs0 = 0.f, rs1 = 0.f;
#pragma unroll
      for (int i = 0; i < 8; i++) { a[i] = __expf(a[i] - mn); rs0 += a[i]; }
#pragma unroll
      for (int i = 8; i < 16; i++) { a[i] = __expf(a[i] - mn); rs1 += a[i]; }
      float rsum = rs0 + rs1;
      rsum += __shfl_xor(rsum, 16, 64);
      rsum += __shfl_xor(rsum, 32, 64);
      mrq = mn;
      lrq = lrq * alpha + rsum;
      // rescale O rows (row q = quad*4+r needs alpha of lane lm=quad*4+r)
#pragma unroll
      for (int r = 0; r < 4; r++) {
        float aw = __shfl(alpha, quad * 4 + r, 64);
        O[0][r] *= aw; O[1][r] *= aw; O[2][r] *= aw; O[3][r] *= aw;
      }
      // P write: lane's 4 consecutive keys per g -> one ds_write_b64
#pragma unroll
      for (int g = 0; g < 4; g++) {
        ushort o4[4] __attribute__((aligned(8)));
#pragma unroll
        for (int r = 0; r < 4; r++) o4[r] = f2bf(a[g * 4 + r]);
        *(uint2*)&Pl[lm * PP + g * 16 + quad * 4] = *(uint2*)o4;
      }
      barrier_lds_only();   // Vst scatter + P stores visible; vmem in flight
      short8 pa0 = *(const short8*)&Pl[lm * PP + quad * 8];
      short8 pa1 = *(const short8*)&Pl[lm * PP + 32 + quad * 8];
#pragma unroll
      for (int d4 = 0; d4 < 4; d4++) {
        short8 bv0 = *(const short8*)&Vst[(d4 * 16 + lm) * VP + quad * 8];
        short8 bv1 = *(const short8*)&Vst[(d4 * 16 + lm) * VP + 32 + quad * 8];
        O[d4] = __builtin_amdgcn_mfma_f32_16x16x32_bf16(pa0, bv0, O[d4], 0, 0, 0);
        O[d4] = __builtin_amdgcn_mfma_f32_16x16x32_bf16(pa1, bv1, O[d4], 0, 0, 0);
      }
      barrier_lds_only();   // all waves' Vst/Pl reads drained (lgkm) -> WAR safe
      vv0 = nv0; vv1 = nv1;
#pragma unroll
      for (int g = 0; g < 4; g++) { kfa[g] = nka[g]; kfb[g] = nkb[g]; }
    }
    float linv = 1.0f / fmaxf(lrq, 1e-20f);
#pragma unroll
    for (int r = 0; r < 4; r++) {
      float lw = __shfl(linv, quad * 4 + r, 64);
#pragma unroll
      for (int d4 = 0; d4 < 4; d4++) {
        ctx[base + (size_t)(qw + quad * 4 + r) * D_MODEL + d4 * 16 + lm] =
            f2bf(O[d4][r] * lw);
      }
    }
  }
}

// ---------------------------------------------------------------------------
extern "C" void kernel_launch(void* const* d_in, const int* in_sizes, int n_in,
                              void* d_out, int out_size, void* d_ws, size_t ws_size,
                              hipStream_t stream) {
  const void* x     = d_in[0];
  const void* ln1_g = d_in[1];
  const void* ln1_b = d_in[2];
  const void* Wq    = d_in[3];
  const void* Wk    = d_in[4];
  const void* Wv    = d_in[5];
  const void* Wo    = d_in[6];
  const void* ln2_g = d_in[7];
  const void* ln2_b = d_in[8];
  const void* W1    = d_in[9];
  const void* b1    = d_in[10];
  const void* W2    = d_in[11];
  const void* b2    = d_in[12];

  const int M = 2 * T_SEQ;  // 4096
  const size_t MEG = 1024 * 1024;
  ushort* W = (ushort*)d_ws;
  ushort* Abuf = W;             // h1 -> ctx -> h2
  ushort* kbuf = W + 4 * MEG;   // k -> x2
  ushort* vbuf = W + 8 * MEG;   // v row-major
  ushort* qbuf = (ushort*)d_out;

  dim3 blk(256);
  dim3 g18(32, 8);
  dim3 attng(T_SEQ / 128, N_HEAD, 2);  // 16 q-tile PAIRS x 16 heads x 2 batch

  bool fast = ws_size >= (size_t)40 * MEG + 4096;

  if (fast) {
    ushort* WqkvT = W + 12 * MEG;             // dead after QKV
    ushort* WoT   = W + 15 * MEG;             // dead after Wo
    ushort* W1T   = W + 16 * MEG;
    ushort* W2T   = W + 18 * MEG;
    ushort* act   = W + 8 * MEG;              // [4096,2048] over v/WqkvT/WoT
    uint* flag = (uint*)(W + 20 * MEG);

    detect_dtype<<<1, 256, 0, stream>>>((const ushort*)x, flag);

    prep_all<<<dim3(12288), blk, 0, stream>>>(
        Wq, Wk, Wv, Wo, W1, W2,
        WqkvT, WqkvT + 1 * MEG, WqkvT + 2 * MEG, WoT, W1T, W2T,
        x, ln1_g, ln1_b, Abuf, flag);

    // QKV: 128x128 tile, KSTEP=32 (768 blocks = 3/CU)
    gemm_tt<0, 1, 128, 32><<<dim3(32, 24), blk, 0, stream>>>(
        Abuf, 1024, WqkvT, 1024, qbuf, kbuf, vbuf, 1024,
        nullptr, 0, nullptr, 0, M, 1024, flag);

    attn_kernel<<<attng, blk, 0, stream>>>(qbuf, kbuf, vbuf, Abuf);

    // Wo: 128x64 tile -> 512 blocks = 2/CU
    gemm_tt<1, 0, 64, 32><<<dim3(32, 16), blk, 0, stream>>>(
        Abuf, 1024, WoT, 1024, kbuf, nullptr, nullptr, 1024,
        nullptr, 0, x, 1024, M, 1024, flag);

    ln_kernel<<<dim3(M), blk, 0, stream>>>(kbuf, ln2_g, ln2_b, Abuf, 0, flag);

    // FF1: 128x128 tile -> (32,16) = 512 blocks = 2/CU at FULL density
    // (r10: density > occupancy at >=2/CU; r4's NT=64 here was unisolated)
    gemm_tt<2, 0, 128, 32><<<dim3(32, 16), blk, 0, stream>>>(
        Abuf, 1024, W1T, 1024, act, nullptr, nullptr, 2048,
        b1, 0, nullptr, 0, M, 1024, flag);
    // FF2: 128x64 tile -> 512 blocks = 2/CU
    gemm_tt<5, 0, 64, 32><<<dim3(32, 16), blk, 0, stream>>>(
        act, 2048, W2T, 2048, d_out, nullptr, nullptr, 1024,
        b2, 0, kbuf, 1024, M, 2048, flag);
  } else {
    uint* flag = (uint*)(W + 12 * MEG);
    detect_dtype<<<1, 256, 0, stream>>>((const ushort*)x, flag);
    ln_kernel<<<dim3(M), blk, 0, stream>>>(x, ln1_g, ln1_b, Abuf, 1, flag);
    gemm_kn<0, 0><<<g18, blk, 0, stream>>>(Abuf, 1024, Wq, 1024, 0, qbuf, 1024,
                                           nullptr, 0, nullptr, 0, M, 1024, flag);
    gemm_kn<0, 0><<<g18, blk, 0, stream>>>(Abuf, 1024, Wk, 1024, 0, kbuf, 1024,
                                           nullptr, 0, nullptr, 0, M, 1024, flag);
    gemm_kn<0, 0><<<g18, blk, 0, stream>>>(Abuf, 1024, Wv, 1024, 0, vbuf, 1024,
                                           nullptr, 0, nullptr, 0, M, 1024, flag);
    attn_kernel<<<attng, blk, 0, stream>>>(qbuf, kbuf, vbuf, Abuf);
    gemm_kn<1, 0><<<g18, blk, 0, stream>>>(Abuf, 1024, Wo, 1024, 0, kbuf, 1024,
                                           nullptr, 0, x, 1024, M, 1024, flag);
    ln_kernel<<<dim3(M), blk, 0, stream>>>(kbuf, ln2_g, ln2_b, Abuf, 0, flag);
    gemm_kn<2, 0><<<g18, blk, 0, stream>>>(Abuf, 1024, W1, 2048, 0, vbuf, 1024,
                                           b1, 0, nullptr, 0, M, 1024, flag);
    gemm_kn<0, 1><<<g18, blk, 0, stream>>>(vbuf, 1024, W2, 1024, 0, d_out, 1024,
                                           nullptr, 0, nullptr, 0, M, 1024, flag);
    gemm_kn<2, 0><<<g18, blk, 0, stream>>>(Abuf, 1024, W1, 2048, 1024, vbuf, 1024,
                                           b1, 1024, nullptr, 0, M, 1024, flag);
    gemm_kn<4, 1><<<g18, blk, 0, stream>>>(vbuf, 1024, W2, 1024, (size_t)1024 * 1024,
                                           d_out, 1024, b2, 0, kbuf, 1024, M, 1024, flag);
  }
}

// Round 13
// 351.912 us; speedup vs baseline: 1.0422x; 1.0422x over previous
//
#include <hip/hip_runtime.h>
#include <hip/hip_bf16.h>

typedef __attribute__((ext_vector_type(8))) short short8;
typedef __attribute__((ext_vector_type(4))) float floatx4;
typedef __attribute__((ext_vector_type(4))) unsigned int uintx4;

#define D_MODEL 1024
#define T_SEQ   2048
#define N_HEAD  16
#define NEG_BIG (-1e30f)
#define LDSP 40 // fallback-gemm pitch
#define VP 72   // V-tile pitch: 144B rows, 16B-aligned -> true ds_read_b128
#define PP 72   // P-tile pitch

static __device__ __forceinline__ float bf2f(ushort u) {
  unsigned int x = ((unsigned int)u) << 16;
  return __builtin_bit_cast(float, x);
}
static __device__ __forceinline__ ushort san(ushort u) {
  return ((u & 0x7F80u) == 0x7F80u) ? (ushort)0 : u;
}
static __device__ __forceinline__ float bf2f_s(ushort u) { return bf2f(san(u)); }
static __device__ __forceinline__ ushort f2bf(float f) {
  unsigned int x = __builtin_bit_cast(unsigned int, f);
  x += 0x7FFFu + ((x >> 16) & 1u);
  return (ushort)(x >> 16);
}
static __device__ __forceinline__ float ext_ld(const void* p, size_t i, int isbf) {
  return isbf ? bf2f_s(((const ushort*)p)[i]) : ((const float*)p)[i];
}
// async global->LDS DMA, 16 B/lane; LDS dest = wave-uniform base + lane*16
static __device__ __forceinline__ void gload16(const void* g, void* l) {
  __builtin_amdgcn_global_load_lds(
      (const __attribute__((address_space(1))) void*)g,
      (__attribute__((address_space(3))) void*)l, 16, 0, 0);
}
// block barrier WITHOUT vmcnt drain: LDS writes visible (lgkmcnt), but
// register-destined global prefetches stay in flight across the barrier.
// r12: attn 99.3->98.0us vs __syncthreads. sched_barrier pins against
// hipcc hoisting past inline-asm waitcnt (rule #18).
static __device__ __forceinline__ void barrier_lds_only() {
  asm volatile("s_waitcnt lgkmcnt(0)" ::: "memory");
  __builtin_amdgcn_s_barrier();
  __builtin_amdgcn_sched_barrier(0);
}

// dtype probe: low ushort of dword -> bf16 data has exp in [0x60,0x8F] ~100%
__global__ void detect_dtype(const ushort* x, uint* flag) {
  int tid = threadIdx.x;
  int cnt = 0;
  for (int j = 0; j < 16; j++) {
    ushort u = x[2 * (tid * 16 + j)];
    int e = (u >> 7) & 0xFF;
    if (e >= 0x60 && e <= 0x8F) cnt++;
  }
  for (int d = 32; d; d >>= 1) cnt += __shfl_xor(cnt, d, 64);
  __shared__ int c[4];
  if ((tid & 63) == 0) c[tid >> 6] = cnt;
  __syncthreads();
  if (tid == 0) flag[0] = (c[0] + c[1] + c[2] + c[3] >= 2048) ? 1u : 0u;
}

// prep_all: ALL weight convert+transpose (blocks 0..8191) + LN1 (8192..12287)
__global__ __launch_bounds__(256) void prep_all(
    const void* __restrict__ Wq, const void* __restrict__ Wk,
    const void* __restrict__ Wv, const void* __restrict__ Wo,
    const void* __restrict__ W1, const void* __restrict__ W2,
    ushort* __restrict__ oq, ushort* __restrict__ ok, ushort* __restrict__ ov,
    ushort* __restrict__ oo, ushort* __restrict__ o1, ushort* __restrict__ o2,
    const void* __restrict__ x, const void* __restrict__ ln_g,
    const void* __restrict__ ln_b, ushort* __restrict__ ln_out,
    const uint* __restrict__ flagp) {
  int isbf = (int)*flagp;
  int id = blockIdx.x;
  int tid = threadIdx.x;

  if (id >= 8192) {
    // ---- LN1 row (ext input: dtype follows flag) ----
    int row = id - 8192;
    size_t ro = (size_t)row * D_MODEL;
    float v[4], gv[4], bv[4];
    if (!isbf) {
      floatx4 xv = *((const floatx4*)((const float*)x + ro) + tid);
#pragma unroll
      for (int i = 0; i < 4; i++) v[i] = xv[i];
    } else {
#pragma unroll
      for (int i = 0; i < 4; i++) v[i] = bf2f_s(((const ushort*)x)[ro + tid * 4 + i]);
    }
    float s = 0.f, sq = 0.f;
#pragma unroll
    for (int i = 0; i < 4; i++) { s += v[i]; sq += v[i] * v[i]; }
#pragma unroll
    for (int d = 32; d; d >>= 1) {
      s += __shfl_xor(s, d, 64);
      sq += __shfl_xor(sq, d, 64);
    }
    __shared__ float red[8];
    int wave = tid >> 6, lane = tid & 63;
    if (lane == 0) { red[wave] = s; red[4 + wave] = sq; }
    __syncthreads();
    s = red[0] + red[1] + red[2] + red[3];
    sq = red[4] + red[5] + red[6] + red[7];
    float mu = s * (1.0f / D_MODEL);
    float var = sq * (1.0f / D_MODEL) - mu * mu;
    float rs = rsqrtf(fmaxf(var, 0.f) + 1e-5f);
    if (!isbf) {
      floatx4 g4 = *((const floatx4*)ln_g + tid);
      floatx4 b4 = *((const floatx4*)ln_b + tid);
#pragma unroll
      for (int i = 0; i < 4; i++) { gv[i] = g4[i]; bv[i] = b4[i]; }
    } else {
#pragma unroll
      for (int i = 0; i < 4; i++) {
        gv[i] = bf2f_s(((const ushort*)ln_g)[tid * 4 + i]);
        bv[i] = bf2f_s(((const ushort*)ln_b)[tid * 4 + i]);
      }
    }
    ushort o4[4];
#pragma unroll
    for (int i = 0; i < 4; i++) o4[i] = f2bf((v[i] - mu) * rs * gv[i] + bv[i]);
    *(uint2*)(ln_out + ro + tid * 4) = *(uint2*)o4;
    return;
  }

  // ---- weight convert+transpose tile ----
  const void* in;
  ushort* out;
  int R, C, local;
  if (id < 4096) {
    int w = id >> 10;
    local = id & 1023;
    R = 1024; C = 1024;
    in  = (w == 0) ? Wq : (w == 1) ? Wk : (w == 2) ? Wv : Wo;
    out = (w == 0) ? oq : (w == 1) ? ok : (w == 2) ? ov : oo;
  } else if (id < 6144) {
    local = id - 4096; R = 1024; C = 2048; in = W1; out = o1;
  } else {
    local = id - 6144; R = 2048; C = 1024; in = W2; out = o2;
  }
  int cb = C >> 5;
  int c0 = (local % cb) * 32, r0 = (local / cb) * 32;
  __shared__ float t[32][33];
  int tx = tid & 31, ty = tid >> 5;
  for (int i = ty; i < 32; i += 8)
    t[i][tx] = ext_ld(in, (size_t)(r0 + i) * C + c0 + tx, isbf);
  __syncthreads();
  for (int i = ty; i < 32; i += 8)
    out[(size_t)(c0 + i) * R + r0 + tx] = f2bf(t[tx][i]);
}

// ---------------- LayerNorm -> bf16 (LN2 only now) ----------------
__global__ __launch_bounds__(256) void ln_kernel(
    const void* __restrict__ x, const void* __restrict__ g,
    const void* __restrict__ bb, ushort* __restrict__ out,
    int ext, const uint* __restrict__ flagp) {
  int wbf = (int)*flagp;
  int xbf = ext ? wbf : 1;
  int row = blockIdx.x, tid = threadIdx.x;
  size_t ro = (size_t)row * D_MODEL;
  float v[4], gv[4], bv[4];
  if (!xbf) {
    floatx4 xv = *((const floatx4*)((const float*)x + ro) + tid);
#pragma unroll
    for (int i = 0; i < 4; i++) v[i] = xv[i];
  } else {
#pragma unroll
    for (int i = 0; i < 4; i++) v[i] = bf2f_s(((const ushort*)x)[ro + tid * 4 + i]);
  }
  float s = 0.f, sq = 0.f;
#pragma unroll
  for (int i = 0; i < 4; i++) { s += v[i]; sq += v[i] * v[i]; }
#pragma unroll
  for (int d = 32; d; d >>= 1) {
    s += __shfl_xor(s, d, 64);
    sq += __shfl_xor(sq, d, 64);
  }
  __shared__ float red[8];
  int wave = tid >> 6, lane = tid & 63;
  if (lane == 0) { red[wave] = s; red[4 + wave] = sq; }
  __syncthreads();
  s = red[0] + red[1] + red[2] + red[3];
  sq = red[4] + red[5] + red[6] + red[7];
  float mu = s * (1.0f / D_MODEL);
  float var = sq * (1.0f / D_MODEL) - mu * mu;
  float rs = rsqrtf(fmaxf(var, 0.f) + 1e-5f);
  if (!wbf) {
    floatx4 g4 = *((const floatx4*)g + tid);
    floatx4 b4 = *((const floatx4*)bb + tid);
#pragma unroll
    for (int i = 0; i < 4; i++) { gv[i] = g4[i]; bv[i] = b4[i]; }
  } else {
#pragma unroll
    for (int i = 0; i < 4; i++) {
      gv[i] = bf2f_s(((const ushort*)g)[tid * 4 + i]);
      bv[i] = bf2f_s(((const ushort*)bb)[tid * 4 + i]);
    }
  }
  ushort o4[4];
#pragma unroll
  for (int i = 0; i < 4; i++) o4[i] = f2bf((v[i] - mu) * rs * gv[i] + bv[i]);
  *(uint2*)(out + ro + tid * 4) = *(uint2*)o4;
}

// ---------------- fast GEMM: C = A[M,K] @ Bt[N,K]^T, both bf16 --------------
// EPI: 0 plain bf16 | 1 +res(ext) bf16 | 2 +bias(ext)+GELU bf16 |
//      5 +bias(ext)+res(bf16) -> store FINAL dtype
// NT: QKV=128@3/CU (r10: NT=64@6/CU regressed). Wo/FF1/FF2=64 (r4 proved for
// Wo/FF2; r12 proved FF1 NT=128@2/CU loses ~14.5us to NT=64@4/CU -- the GELU
// epilogue's VALU tail needs the extra co-resident blocks). KSTEP=32 (r8).
template <int EPI, int SPLIT, int NT, int KSTEP>
__global__ __launch_bounds__(256) void gemm_tt(
    const ushort* __restrict__ A, int lda,
    const ushort* __restrict__ Bt, int ldbt,
    void* __restrict__ C0v, ushort* __restrict__ C1, ushort* __restrict__ C2,
    int ldc,
    const void* __restrict__ bias, size_t biasoff,
    const void* __restrict__ res, int ldr,
    int M, int K, const uint* __restrict__ flagp) {
  __shared__ __align__(16) ushort As[128 * KSTEP];
  __shared__ __align__(16) ushort Bs[NT * KSTEP];
  int isbf = (int)*flagp;
  int tid = threadIdx.x;
  int wave = tid >> 6, lane = tid & 63, lm = lane & 15, quad = lane >> 4;
  int m0 = blockIdx.x * 128, n0 = blockIdx.y * NT;
  constexpr int MR = (NT == 128) ? 4 : 2;
  constexpr int RPW = 512 / KSTEP;   // rows per wave-DMA
  constexpr int RPC = 4 * RPW;       // rows per gload16 call (4 waves)
  constexpr int LPR = KSTEP / 8;     // lanes per row
  int wm = (NT == 128) ? (wave >> 1) * 64 : wave * 32;
  int wn = (NT == 128) ? (wave & 1) * 64 : 0;
  floatx4 acc[MR][4] = {};
  int srl = lane / LPR;
  int scl = (lane % LPR) * 8;

  for (int kk = 0; kk < K; kk += KSTEP) {
#pragma unroll
    for (int i = 0; i < 128 / RPC; i++)
      gload16(A + (size_t)(m0 + i * RPC + wave * RPW + srl) * lda + kk + scl,
              &As[(i * RPC + wave * RPW) * KSTEP]);
#pragma unroll
    for (int i = 0; i < NT / RPC; i++)
      gload16(Bt + (size_t)(n0 + i * RPC + wave * RPW + srl) * ldbt + kk + scl,
              &Bs[(i * RPC + wave * RPW) * KSTEP]);
    __syncthreads();
#pragma unroll
    for (int kk2 = 0; kk2 < KSTEP; kk2 += 32) {
      short8 af[MR], bf[4];
#pragma unroll
      for (int i = 0; i < MR; i++)
        af[i] = *(const short8*)&As[(wm + i * 16 + lm) * KSTEP + kk2 + quad * 8];
#pragma unroll
      for (int i = 0; i < 4; i++)
        bf[i] = *(const short8*)&Bs[(wn + i * 16 + lm) * KSTEP + kk2 + quad * 8];
#pragma unroll
      for (int mi = 0; mi < MR; mi++)
#pragma unroll
        for (int ni = 0; ni < 4; ni++)
          acc[mi][ni] = __builtin_amdgcn_mfma_f32_16x16x32_bf16(
              af[mi], bf[ni], acc[mi][ni], 0, 0, 0);
    }
    __syncthreads();
  }

  ushort* Cseg = (ushort*)C0v;
  int colbase = n0;
  if (SPLIT) {
    int seg = n0 >> 10;
    Cseg = (seg == 0) ? (ushort*)C0v : (seg == 1 ? C1 : C2);
    colbase = n0 & 1023;
  }
#pragma unroll
  for (int mi = 0; mi < MR; mi++) {
#pragma unroll
    for (int ni = 0; ni < 4; ni++) {
      int col = colbase + wn + ni * 16 + lm;
#pragma unroll
      for (int r = 0; r < 4; r++) {
        int row = m0 + wm + mi * 16 + quad * 4 + r;
        size_t ci = (size_t)row * ldc + col;
        float v = acc[mi][ni][r];
        if (EPI == 2 || EPI == 5) v += ext_ld(bias, biasoff + col, isbf);
        if (EPI == 1) v += ext_ld(res, (size_t)row * ldr + col, isbf);
        if (EPI == 5) v += bf2f(((const ushort*)res)[(size_t)row * ldr + col]);
        if (EPI == 2) v = 0.5f * v * (1.0f + erff(v * 0.70710678118654752f));
        if (EPI == 5 && !isbf) ((float*)C0v)[ci] = v;
        else                   Cseg[ci] = f2bf(v);
      }
    }
  }
}

// ---------------- fallback GEMM: B in [K,N] external dtype ------------------
template <int EPI, int FINAL>
__global__ __launch_bounds__(256) void gemm_kn(
    const ushort* __restrict__ A, int lda,
    const void* __restrict__ B, int ldb, size_t boff,
    void* __restrict__ C, int ldc,
    const void* __restrict__ bias, size_t biasoff,
    const void* __restrict__ res, int ldr,
    int M, int K, const uint* __restrict__ flagp) {
  __shared__ __align__(16) ushort As[128 * LDSP];
  __shared__ __align__(16) ushort Bs[128 * LDSP];
  int isbf = (int)*flagp;
  int tid = threadIdx.x;
  int wave = tid >> 6, lane = tid & 63, lm = lane & 15, quad = lane >> 4;
  int m0 = blockIdx.x * 128, n0 = blockIdx.y * 128;
  int wm = (wave >> 1) * 64, wn = (wave & 1) * 64;
  floatx4 acc[4][4] = {};
  int sr = tid >> 2;
  int sc = (tid & 3) * 8;
  int bk = tid >> 4;
  int bn8 = (tid & 15) * 8;

  for (int kk = 0; kk < K; kk += 32) {
    uintx4 va0 = *(const uintx4*)(A + (size_t)(m0 + sr) * lda + kk + sc);
    uintx4 va1 = *(const uintx4*)(A + (size_t)(m0 + sr + 64) * lda + kk + sc);
    *(uintx4*)&As[sr * LDSP + sc] = va0;
    *(uintx4*)&As[(sr + 64) * LDSP + sc] = va1;
    if (isbf) {
      const ushort* Bu = (const ushort*)B;
#pragma unroll
      for (int p = 0; p < 2; p++) {
        int krow = bk + p * 16;
        uintx4 raw = *(const uintx4*)(Bu + boff + (size_t)(kk + krow) * ldb + n0 + bn8);
        ushort tmp[8] __attribute__((aligned(16)));
        *(uintx4*)tmp = raw;
#pragma unroll
        for (int i = 0; i < 8; i++) Bs[(bn8 + i) * LDSP + krow] = san(tmp[i]);
      }
    } else {
      const float* Bf = (const float*)B;
#pragma unroll
      for (int p = 0; p < 2; p++) {
        int krow = bk + p * 16;
        const float* src = Bf + boff + (size_t)(kk + krow) * ldb + n0 + bn8;
        floatx4 f0 = *(const floatx4*)src;
        floatx4 f1 = *(const floatx4*)(src + 4);
#pragma unroll
        for (int i = 0; i < 4; i++) {
          Bs[(bn8 + i) * LDSP + krow] = f2bf(f0[i]);
          Bs[(bn8 + 4 + i) * LDSP + krow] = f2bf(f1[i]);
        }
      }
    }
    __syncthreads();
    short8 af[4], bf[4];
#pragma unroll
    for (int i = 0; i < 4; i++)
      af[i] = *(const short8*)&As[(wm + i * 16 + lm) * LDSP + quad * 8];
#pragma unroll
    for (int i = 0; i < 4; i++)
      bf[i] = *(const short8*)&Bs[(wn + i * 16 + lm) * LDSP + quad * 8];
#pragma unroll
    for (int mi = 0; mi < 4; mi++)
#pragma unroll
      for (int ni = 0; ni < 4; ni++)
        acc[mi][ni] = __builtin_amdgcn_mfma_f32_16x16x32_bf16(
            af[mi], bf[ni], acc[mi][ni], 0, 0, 0);
    __syncthreads();
  }

#pragma unroll
  for (int mi = 0; mi < 4; mi++) {
#pragma unroll
    for (int ni = 0; ni < 4; ni++) {
      int col = n0 + wn + ni * 16 + lm;
#pragma unroll
      for (int r = 0; r < 4; r++) {
        int row = m0 + wm + mi * 16 + quad * 4 + r;
        size_t ci = (size_t)row * ldc + col;
        float v = acc[mi][ni][r];
        if (EPI == 4)
          v += (FINAL && !isbf) ? ((const float*)C)[ci] : bf2f(((const ushort*)C)[ci]);
        if (EPI == 2 || EPI == 4) v += ext_ld(bias, biasoff + col, isbf);
        if (EPI == 1) v += ext_ld(res, (size_t)row * ldr + col, isbf);
        if (EPI == 4) v += bf2f(((const ushort*)res)[(size_t)row * ldr + col]);
        if (EPI == 2) v = 0.5f * v * (1.0f + erff(v * 0.70710678118654752f));
        if (FINAL && !isbf) ((float*)C)[ci] = v;
        else                ((ushort*)C)[ci] = f2bf(v);
      }
    }
  }
}

// ---------------- causal flash attention (best-known: 98.0us) ---------------
// r7 structure (uniform pairing, swapped softmax, single Vst, 2 barriers per
// tile) + r12's barrier_lds_only (no vmcnt drain at barriers; register
// prefetches stay in flight). DO NOT touch further.
__global__ __launch_bounds__(256) void attn_kernel(
    const ushort* __restrict__ q, const ushort* __restrict__ k,
    const ushort* __restrict__ v, ushort* __restrict__ ctx) {
  int tid = threadIdx.x, wave = tid >> 6, lane = tid & 63;
  int lm = lane & 15, quad = lane >> 4;
  int bx = blockIdx.x, h = blockIdx.y, b = blockIdx.z;
  size_t base = (size_t)b * T_SEQ * D_MODEL + h * 64;

  __shared__ __align__(16) ushort Vst[64 * VP];      // [hd][key]
  __shared__ __align__(16) ushort PlAll[4][16 * PP]; // per-wave P
  ushort* Pl = PlAll[wave];

  int vr_r = tid & 63, vcg = (tid >> 6) * 16;
  const ushort* vrow = v + base + vcg;

#pragma unroll
  for (int qsel = 0; qsel < 2; ++qsel) {
    int qt = qsel ? (31 - bx) : bx;
    int qw = qt * 64 + wave * 16;

    short8 aq0 = *(const short8*)&q[base + (size_t)(qw + lm) * D_MODEL + quad * 8];
    short8 aq1 = *(const short8*)&q[base + (size_t)(qw + lm) * D_MODEL + 32 + quad * 8];

    floatx4 O[4] = {};
    float mrq = NEG_BIG, lrq = 0.f;  // running max/denom for query qw+lm

    int ntiles = qt + 1;

    // prefetch tile 0
    uintx4 vv0 = *(const uintx4*)(vrow + (size_t)vr_r * D_MODEL);
    uintx4 vv1 = *(const uintx4*)(vrow + (size_t)vr_r * D_MODEL + 8);
    short8 kfa[4], kfb[4];
#pragma unroll
    for (int g = 0; g < 4; g++) {
      const ushort* kr = &k[base + (size_t)(g * 16 + lm) * D_MODEL + quad * 8];
      kfa[g] = *(const short8*)kr;
      kfb[g] = *(const short8*)(kr + 32);
    }

    for (int kt = 0; kt < ntiles; ++kt) {
      int k0 = kt * 64;
      // scatter prefetched V into shared Vst (all 256 threads)
      {
        ushort t0[8] __attribute__((aligned(16)));
        ushort t1[8] __attribute__((aligned(16)));
        *(uintx4*)t0 = vv0;
        *(uintx4*)t1 = vv1;
#pragma unroll
        for (int i = 0; i < 8; i++) {
          Vst[(vcg + i) * VP + vr_r] = t0[i];
          Vst[(vcg + 8 + i) * VP + vr_r] = t1[i];
        }
      }
      // QK^T SWAPPED: sc[g] = S^T[key=g*16+quad*4+r][query=lm]
      floatx4 sc[4];
#pragma unroll
      for (int g = 0; g < 4; g++) {
        floatx4 z = {};
        sc[g] = __builtin_amdgcn_mfma_f32_16x16x32_bf16(kfa[g], aq0, z, 0, 0, 0);
        sc[g] = __builtin_amdgcn_mfma_f32_16x16x32_bf16(kfb[g], aq1, sc[g], 0, 0, 0);
      }
      // issue prefetch for next tile (stays in flight across barriers)
      int k0n = (kt + 1 < ntiles) ? k0 + 64 : k0;
      uintx4 nv0 = *(const uintx4*)(vrow + (size_t)(k0n + vr_r) * D_MODEL);
      uintx4 nv1 = *(const uintx4*)(vrow + (size_t)(k0n + vr_r) * D_MODEL + 8);
      short8 nka[4], nkb[4];
#pragma unroll
      for (int g = 0; g < 4; g++) {
        const ushort* kr = &k[base + (size_t)(k0n + g * 16 + lm) * D_MODEL + quad * 8];
        nka[g] = *(const short8*)kr;
        nkb[g] = *(const short8*)(kr + 32);
      }
      // online softmax: lane owns query qw+lm, 16 keys in-lane
      bool full = (k0 + 63 <= qw);
      int qrow = qw + lm;
      float a[16];
#pragma unroll
      for (int g = 0; g < 4; g++)
#pragma unroll
        for (int r = 0; r < 4; r++) {
          float s = sc[g][r] * 0.125f;
          if (!full && (k0 + g * 16 + quad * 4 + r > qrow)) s = NEG_BIG;
          a[g * 4 + r] = s;
        }
      float m0 = fmaxf(fmaxf(a[0], a[1]), fmaxf(a[2], a[3]));
      float m1 = fmaxf(fmaxf(a[4], a[5]), fmaxf(a[6], a[7]));
      float m2 = fmaxf(fmaxf(a[8], a[9]), fmaxf(a[10], a[11]));
      float m3 = fmaxf(fmaxf(a[12], a[13]), fmaxf(a[14], a[15]));
      float tm = fmaxf(fmaxf(m0, m1), fmaxf(m2, m3));
      tm = fmaxf(tm, __shfl_xor(tm, 16, 64));
      tm = fmaxf(tm, __shfl_xor(tm, 32, 64));
      float mn = fmaxf(mrq, tm);
      float alpha = __expf(mrq - mn);
      float rs0 = 0.f, rs1 = 0.f;
#pragma unroll
      for (int i = 0; i < 8; i++) { a[i] = __expf(a[i] - mn); rs0 += a[i]; }
#pragma unroll
      for (int i = 8; i < 16; i++) { a[i] = __expf(a[i] - mn); rs1 += a[i]; }
      float rsum = rs0 + rs1;
      rsum += __shfl_xor(rsum, 16, 64);
      rsum += __shfl_xor(rsum, 32, 64);
      mrq = mn;
      lrq = lrq * alpha + rsum;
      // rescale O rows (row q = quad*4+r needs alpha of lane lm=quad*4+r)
#pragma unroll
      for (int r = 0; r < 4; r++) {
        float aw = __shfl(alpha, quad * 4 + r, 64);
        O[0][r] *= aw; O[1][r] *= aw; O[2][r] *= aw; O[3][r] *= aw;
      }
      // P write: lane's 4 consecutive keys per g -> one ds_write_b64
#pragma unroll
      for (int g = 0; g < 4; g++) {
        ushort o4[4] __attribute__((aligned(8)));
#pragma unroll
        for (int r = 0; r < 4; r++) o4[r] = f2bf(a[g * 4 + r]);
        *(uint2*)&Pl[lm * PP + g * 16 + quad * 4] = *(uint2*)o4;
      }
      barrier_lds_only();   // Vst scatter + P stores visible; vmem in flight
      short8 pa0 = *(const short8*)&Pl[lm * PP + quad * 8];
      short8 pa1 = *(const short8*)&Pl[lm * PP + 32 + quad * 8];
#pragma unroll
      for (int d4 = 0; d4 < 4; d4++) {
        short8 bv0 = *(const short8*)&Vst[(d4 * 16 + lm) * VP + quad * 8];
        short8 bv1 = *(const short8*)&Vst[(d4 * 16 + lm) * VP + 32 + quad * 8];
        O[d4] = __builtin_amdgcn_mfma_f32_16x16x32_bf16(pa0, bv0, O[d4], 0, 0, 0);
        O[d4] = __builtin_amdgcn_mfma_f32_16x16x32_bf16(pa1, bv1, O[d4], 0, 0, 0);
      }
      barrier_lds_only();   // all waves' Vst/Pl reads drained (lgkm) -> WAR safe
      vv0 = nv0; vv1 = nv1;
#pragma unroll
      for (int g = 0; g < 4; g++) { kfa[g] = nka[g]; kfb[g] = nkb[g]; }
    }
    float linv = 1.0f / fmaxf(lrq, 1e-20f);
#pragma unroll
    for (int r = 0; r < 4; r++) {
      float lw = __shfl(linv, quad * 4 + r, 64);
#pragma unroll
      for (int d4 = 0; d4 < 4; d4++) {
        ctx[base + (size_t)(qw + quad * 4 + r) * D_MODEL + d4 * 16 + lm] =
            f2bf(O[d4][r] * lw);
      }
    }
  }
}

// ---------------------------------------------------------------------------
extern "C" void kernel_launch(void* const* d_in, const int* in_sizes, int n_in,
                              void* d_out, int out_size, void* d_ws, size_t ws_size,
                              hipStream_t stream) {
  const void* x     = d_in[0];
  const void* ln1_g = d_in[1];
  const void* ln1_b = d_in[2];
  const void* Wq    = d_in[3];
  const void* Wk    = d_in[4];
  const void* Wv    = d_in[5];
  const void* Wo    = d_in[6];
  const void* ln2_g = d_in[7];
  const void* ln2_b = d_in[8];
  const void* W1    = d_in[9];
  const void* b1    = d_in[10];
  const void* W2    = d_in[11];
  const void* b2    = d_in[12];

  const int M = 2 * T_SEQ;  // 4096
  const size_t MEG = 1024 * 1024;
  ushort* W = (ushort*)d_ws;
  ushort* Abuf = W;             // h1 -> ctx -> h2
  ushort* kbuf = W + 4 * MEG;   // k -> x2
  ushort* vbuf = W + 8 * MEG;   // v row-major
  ushort* qbuf = (ushort*)d_out;

  dim3 blk(256);
  dim3 g18(32, 8);
  dim3 attng(T_SEQ / 128, N_HEAD, 2);  // 16 q-tile PAIRS x 16 heads x 2 batch

  bool fast = ws_size >= (size_t)40 * MEG + 4096;

  if (fast) {
    ushort* WqkvT = W + 12 * MEG;             // dead after QKV
    ushort* WoT   = W + 15 * MEG;             // dead after Wo
    ushort* W1T   = W + 16 * MEG;
    ushort* W2T   = W + 18 * MEG;
    ushort* act   = W + 8 * MEG;              // [4096,2048] over v/WqkvT/WoT
    uint* flag = (uint*)(W + 20 * MEG);

    detect_dtype<<<1, 256, 0, stream>>>((const ushort*)x, flag);

    prep_all<<<dim3(12288), blk, 0, stream>>>(
        Wq, Wk, Wv, Wo, W1, W2,
        WqkvT, WqkvT + 1 * MEG, WqkvT + 2 * MEG, WoT, W1T, W2T,
        x, ln1_g, ln1_b, Abuf, flag);

    // QKV: 128x128 tile, KSTEP=32 (768 blocks = 3/CU)
    gemm_tt<0, 1, 128, 32><<<dim3(32, 24), blk, 0, stream>>>(
        Abuf, 1024, WqkvT, 1024, qbuf, kbuf, vbuf, 1024,
        nullptr, 0, nullptr, 0, M, 1024, flag);

    attn_kernel<<<attng, blk, 0, stream>>>(qbuf, kbuf, vbuf, Abuf);

    // Wo: 128x64 tile -> 512 blocks = 2/CU
    gemm_tt<1, 0, 64, 32><<<dim3(32, 16), blk, 0, stream>>>(
        Abuf, 1024, WoT, 1024, kbuf, nullptr, nullptr, 1024,
        nullptr, 0, x, 1024, M, 1024, flag);

    ln_kernel<<<dim3(M), blk, 0, stream>>>(kbuf, ln2_g, ln2_b, Abuf, 0, flag);

    // FF1: 128x64 tile -> 1024 blocks = 4/CU (r12: NT=128@2/CU lost 14.5us)
    gemm_tt<2, 0, 64, 32><<<dim3(32, 32), blk, 0, stream>>>(
        Abuf, 1024, W1T, 1024, act, nullptr, nullptr, 2048,
        b1, 0, nullptr, 0, M, 1024, flag);
    // FF2: 128x64 tile -> 512 blocks = 2/CU
    gemm_tt<5, 0, 64, 32><<<dim3(32, 16), blk, 0, stream>>>(
        act, 2048, W2T, 2048, d_out, nullptr, nullptr, 1024,
        b2, 0, kbuf, 1024, M, 2048, flag);
  } else {
    uint* flag = (uint*)(W + 12 * MEG);
    detect_dtype<<<1, 256, 0, stream>>>((const ushort*)x, flag);
    ln_kernel<<<dim3(M), blk, 0, stream>>>(x, ln1_g, ln1_b, Abuf, 1, flag);
    gemm_kn<0, 0><<<g18, blk, 0, stream>>>(Abuf, 1024, Wq, 1024, 0, qbuf, 1024,
                                           nullptr, 0, nullptr, 0, M, 1024, flag);
    gemm_kn<0, 0><<<g18, blk, 0, stream>>>(Abuf, 1024, Wk, 1024, 0, kbuf, 1024,
                                           nullptr, 0, nullptr, 0, M, 1024, flag);
    gemm_kn<0, 0><<<g18, blk, 0, stream>>>(Abuf, 1024, Wv, 1024, 0, vbuf, 1024,
                                           nullptr, 0, nullptr, 0, M, 1024, flag);
    attn_kernel<<<attng, blk, 0, stream>>>(qbuf, kbuf, vbuf, Abuf);
    gemm_kn<1, 0><<<g18, blk, 0, stream>>>(Abuf, 1024, Wo, 1024, 0, kbuf, 1024,
                                           nullptr, 0, x, 1024, M, 1024, flag);
    ln_kernel<<<dim3(M), blk, 0, stream>>>(kbuf, ln2_g, ln2_b, Abuf, 0, flag);
    gemm_kn<2, 0><<<g18, blk, 0, stream>>>(Abuf, 1024, W1, 2048, 0, vbuf, 1024,
                                           b1, 0, nullptr, 0, M, 1024, flag);
    gemm_kn<0, 1><<<g18, blk, 0, stream>>>(vbuf, 1024, W2, 1024, 0, d_out, 1024,
                                           nullptr, 0, nullptr, 0, M, 1024, flag);
    gemm_kn<2, 0><<<g18, blk, 0, stream>>>(Abuf, 1024, W1, 2048, 1024, vbuf, 1024,
                                           b1, 1024, nullptr, 0, M, 1024, flag);
    gemm_kn<4, 1><<<g18, blk, 0, stream>>>(vbuf, 1024, W2, 1024, (size_t)1024 * 1024,
                                           d_out, 1024, b2, 0, kbuf, 1024, M, 1024, flag);
  }
}

// Round 14
// 345.411 us; speedup vs baseline: 1.0619x; 1.0188x over previous
//
#include <hip/hip_runtime.h>
#include <hip/hip_bf16.h>

typedef __attribute__((ext_vector_type(8))) short short8;
typedef __attribute__((ext_vector_type(4))) float floatx4;
typedef __attribute__((ext_vector_type(4))) unsigned int uintx4;

#define D_MODEL 1024
#define T_SEQ   2048
#define N_HEAD  16
#define NEG_BIG (-1e30f)
#define LDSP 40 // fallback-gemm pitch
#define VP 72   // V-tile pitch: 144B rows, 16B-aligned -> true ds_read_b128
#define PP 72   // P-tile pitch

static __device__ __forceinline__ float bf2f(ushort u) {
  unsigned int x = ((unsigned int)u) << 16;
  return __builtin_bit_cast(float, x);
}
static __device__ __forceinline__ ushort san(ushort u) {
  return ((u & 0x7F80u) == 0x7F80u) ? (ushort)0 : u;
}
static __device__ __forceinline__ float bf2f_s(ushort u) { return bf2f(san(u)); }
static __device__ __forceinline__ ushort f2bf(float f) {
  unsigned int x = __builtin_bit_cast(unsigned int, f);
  x += 0x7FFFu + ((x >> 16) & 1u);
  return (ushort)(x >> 16);
}
static __device__ __forceinline__ float ext_ld(const void* p, size_t i, int isbf) {
  return isbf ? bf2f_s(((const ushort*)p)[i]) : ((const float*)p)[i];
}
// exact bf16 *0.125: decrement exponent by 3 (power-of-2 -> lossless).
// Guard: tiny/zero exponents flush to signed zero (|x|<2^-123, negligible).
static __device__ __forceinline__ short8 qscale8(short8 v) {
  short8 o;
#pragma unroll
  for (int i = 0; i < 8; i++) {
    ushort u = (ushort)v[i];
    int e = (u >> 7) & 0xFF;
    o[i] = (short)((e > 3) ? (ushort)(u - (3 << 7)) : (ushort)(u & 0x8000u));
  }
  return o;
}
// async global->LDS DMA, 16 B/lane; LDS dest = wave-uniform base + lane*16
static __device__ __forceinline__ void gload16(const void* g, void* l) {
  __builtin_amdgcn_global_load_lds(
      (const __attribute__((address_space(1))) void*)g,
      (__attribute__((address_space(3))) void*)l, 16, 0, 0);
}
// block barrier WITHOUT vmcnt drain: LDS writes visible (lgkmcnt), but
// register-destined global prefetches stay in flight across the barrier.
// r12: attn 99.3->98.0us vs __syncthreads. sched_barrier pins against
// hipcc hoisting past inline-asm waitcnt (rule #18).
static __device__ __forceinline__ void barrier_lds_only() {
  asm volatile("s_waitcnt lgkmcnt(0)" ::: "memory");
  __builtin_amdgcn_s_barrier();
  __builtin_amdgcn_sched_barrier(0);
}

// dtype probe: low ushort of dword -> bf16 data has exp in [0x60,0x8F] ~100%
__global__ void detect_dtype(const ushort* x, uint* flag) {
  int tid = threadIdx.x;
  int cnt = 0;
  for (int j = 0; j < 16; j++) {
    ushort u = x[2 * (tid * 16 + j)];
    int e = (u >> 7) & 0xFF;
    if (e >= 0x60 && e <= 0x8F) cnt++;
  }
  for (int d = 32; d; d >>= 1) cnt += __shfl_xor(cnt, d, 64);
  __shared__ int c[4];
  if ((tid & 63) == 0) c[tid >> 6] = cnt;
  __syncthreads();
  if (tid == 0) flag[0] = (c[0] + c[1] + c[2] + c[3] >= 2048) ? 1u : 0u;
}

// prep_all: weight convert+transpose in 64x64 tiles (both read and transposed
// write issue full 128B/wave segments; 32x32 tiles only reached 64B) +
// LN1 rows. Blocks: 0..1023 Wq/Wk/Wv/Wo, 1024..1535 W1, 1536..2047 W2,
// 2048..6143 LN1.
__global__ __launch_bounds__(256) void prep_all(
    const void* __restrict__ Wq, const void* __restrict__ Wk,
    const void* __restrict__ Wv, const void* __restrict__ Wo,
    const void* __restrict__ W1, const void* __restrict__ W2,
    ushort* __restrict__ oq, ushort* __restrict__ ok, ushort* __restrict__ ov,
    ushort* __restrict__ oo, ushort* __restrict__ o1, ushort* __restrict__ o2,
    const void* __restrict__ x, const void* __restrict__ ln_g,
    const void* __restrict__ ln_b, ushort* __restrict__ ln_out,
    const uint* __restrict__ flagp) {
  int isbf = (int)*flagp;
  int id = blockIdx.x;
  int tid = threadIdx.x;

  if (id >= 2048) {
    // ---- LN1 row (ext input: dtype follows flag) ----
    int row = id - 2048;
    size_t ro = (size_t)row * D_MODEL;
    float v[4], gv[4], bv[4];
    if (!isbf) {
      floatx4 xv = *((const floatx4*)((const float*)x + ro) + tid);
#pragma unroll
      for (int i = 0; i < 4; i++) v[i] = xv[i];
    } else {
#pragma unroll
      for (int i = 0; i < 4; i++) v[i] = bf2f_s(((const ushort*)x)[ro + tid * 4 + i]);
    }
    float s = 0.f, sq = 0.f;
#pragma unroll
    for (int i = 0; i < 4; i++) { s += v[i]; sq += v[i] * v[i]; }
#pragma unroll
    for (int d = 32; d; d >>= 1) {
      s += __shfl_xor(s, d, 64);
      sq += __shfl_xor(sq, d, 64);
    }
    __shared__ float red[8];
    int wave = tid >> 6, lane = tid & 63;
    if (lane == 0) { red[wave] = s; red[4 + wave] = sq; }
    __syncthreads();
    s = red[0] + red[1] + red[2] + red[3];
    sq = red[4] + red[5] + red[6] + red[7];
    float mu = s * (1.0f / D_MODEL);
    float var = sq * (1.0f / D_MODEL) - mu * mu;
    float rs = rsqrtf(fmaxf(var, 0.f) + 1e-5f);
    if (!isbf) {
      floatx4 g4 = *((const floatx4*)ln_g + tid);
      floatx4 b4 = *((const floatx4*)ln_b + tid);
#pragma unroll
      for (int i = 0; i < 4; i++) { gv[i] = g4[i]; bv[i] = b4[i]; }
    } else {
#pragma unroll
      for (int i = 0; i < 4; i++) {
        gv[i] = bf2f_s(((const ushort*)ln_g)[tid * 4 + i]);
        bv[i] = bf2f_s(((const ushort*)ln_b)[tid * 4 + i]);
      }
    }
    ushort o4[4];
#pragma unroll
    for (int i = 0; i < 4; i++) o4[i] = f2bf((v[i] - mu) * rs * gv[i] + bv[i]);
    *(uint2*)(ln_out + ro + tid * 4) = *(uint2*)o4;
    return;
  }

  // ---- weight convert+transpose tile (64x64) ----
  const void* in;
  ushort* out;
  int R, C, local;
  if (id < 1024) {
    int w = id >> 8;
    local = id & 255;
    R = 1024; C = 1024;
    in  = (w == 0) ? Wq : (w == 1) ? Wk : (w == 2) ? Wv : Wo;
    out = (w == 0) ? oq : (w == 1) ? ok : (w == 2) ? ov : oo;
  } else if (id < 1536) {
    local = id - 1024; R = 1024; C = 2048; in = W1; out = o1;
  } else {
    local = id - 1536; R = 2048; C = 1024; in = W2; out = o2;
  }
  int cb = C >> 6;
  int c0 = (local % cb) * 64, r0 = (local / cb) * 64;
  __shared__ float t[64][65];
  int cc = tid & 63, ty = tid >> 6;
  for (int rr = ty; rr < 64; rr += 4)
    t[rr][cc] = ext_ld(in, (size_t)(r0 + rr) * C + c0 + cc, isbf);
  __syncthreads();
  for (int i = ty; i < 64; i += 4)
    out[(size_t)(c0 + i) * R + r0 + cc] = f2bf(t[cc][i]);
}

// ---------------- LayerNorm -> bf16 (LN2 only now) ----------------
__global__ __launch_bounds__(256) void ln_kernel(
    const void* __restrict__ x, const void* __restrict__ g,
    const void* __restrict__ bb, ushort* __restrict__ out,
    int ext, const uint* __restrict__ flagp) {
  int wbf = (int)*flagp;
  int xbf = ext ? wbf : 1;
  int row = blockIdx.x, tid = threadIdx.x;
  size_t ro = (size_t)row * D_MODEL;
  float v[4], gv[4], bv[4];
  if (!xbf) {
    floatx4 xv = *((const floatx4*)((const float*)x + ro) + tid);
#pragma unroll
    for (int i = 0; i < 4; i++) v[i] = xv[i];
  } else {
#pragma unroll
    for (int i = 0; i < 4; i++) v[i] = bf2f_s(((const ushort*)x)[ro + tid * 4 + i]);
  }
  float s = 0.f, sq = 0.f;
#pragma unroll
  for (int i = 0; i < 4; i++) { s += v[i]; sq += v[i] * v[i]; }
#pragma unroll
  for (int d = 32; d; d >>= 1) {
    s += __shfl_xor(s, d, 64);
    sq += __shfl_xor(sq, d, 64);
  }
  __shared__ float red[8];
  int wave = tid >> 6, lane = tid & 63;
  if (lane == 0) { red[wave] = s; red[4 + wave] = sq; }
  __syncthreads();
  s = red[0] + red[1] + red[2] + red[3];
  sq = red[4] + red[5] + red[6] + red[7];
  float mu = s * (1.0f / D_MODEL);
  float var = sq * (1.0f / D_MODEL) - mu * mu;
  float rs = rsqrtf(fmaxf(var, 0.f) + 1e-5f);
  if (!wbf) {
    floatx4 g4 = *((const floatx4*)g + tid);
    floatx4 b4 = *((const floatx4*)bb + tid);
#pragma unroll
    for (int i = 0; i < 4; i++) { gv[i] = g4[i]; bv[i] = b4[i]; }
  } else {
#pragma unroll
    for (int i = 0; i < 4; i++) {
      gv[i] = bf2f_s(((const ushort*)g)[tid * 4 + i]);
      bv[i] = bf2f_s(((const ushort*)bb)[tid * 4 + i]);
    }
  }
  ushort o4[4];
#pragma unroll
  for (int i = 0; i < 4; i++) o4[i] = f2bf((v[i] - mu) * rs * gv[i] + bv[i]);
  *(uint2*)(out + ro + tid * 4) = *(uint2*)o4;
}

// ---------------- fast GEMM: C = A[M,K] @ Bt[N,K]^T, both bf16 --------------
// EPI: 0 plain bf16 | 1 +res(ext) bf16 | 2 +bias(ext)+GELU bf16 |
//      5 +bias(ext)+res(bf16) -> store FINAL dtype
// NT: QKV=128@3/CU (r10: NT=64@6/CU regressed). Wo/FF1/FF2=64 (r4 proved for
// Wo/FF2; r12 proved FF1 NT=128@2/CU loses ~14.5us to NT=64@4/CU). KSTEP=32.
template <int EPI, int SPLIT, int NT, int KSTEP>
__global__ __launch_bounds__(256) void gemm_tt(
    const ushort* __restrict__ A, int lda,
    const ushort* __restrict__ Bt, int ldbt,
    void* __restrict__ C0v, ushort* __restrict__ C1, ushort* __restrict__ C2,
    int ldc,
    const void* __restrict__ bias, size_t biasoff,
    const void* __restrict__ res, int ldr,
    int M, int K, const uint* __restrict__ flagp) {
  __shared__ __align__(16) ushort As[128 * KSTEP];
  __shared__ __align__(16) ushort Bs[NT * KSTEP];
  int isbf = (int)*flagp;
  int tid = threadIdx.x;
  int wave = tid >> 6, lane = tid & 63, lm = lane & 15, quad = lane >> 4;
  int m0 = blockIdx.x * 128, n0 = blockIdx.y * NT;
  constexpr int MR = (NT == 128) ? 4 : 2;
  constexpr int RPW = 512 / KSTEP;   // rows per wave-DMA
  constexpr int RPC = 4 * RPW;       // rows per gload16 call (4 waves)
  constexpr int LPR = KSTEP / 8;     // lanes per row
  int wm = (NT == 128) ? (wave >> 1) * 64 : wave * 32;
  int wn = (NT == 128) ? (wave & 1) * 64 : 0;
  floatx4 acc[MR][4] = {};
  int srl = lane / LPR;
  int scl = (lane % LPR) * 8;

  for (int kk = 0; kk < K; kk += KSTEP) {
#pragma unroll
    for (int i = 0; i < 128 / RPC; i++)
      gload16(A + (size_t)(m0 + i * RPC + wave * RPW + srl) * lda + kk + scl,
              &As[(i * RPC + wave * RPW) * KSTEP]);
#pragma unroll
    for (int i = 0; i < NT / RPC; i++)
      gload16(Bt + (size_t)(n0 + i * RPC + wave * RPW + srl) * ldbt + kk + scl,
              &Bs[(i * RPC + wave * RPW) * KSTEP]);
    __syncthreads();
#pragma unroll
    for (int kk2 = 0; kk2 < KSTEP; kk2 += 32) {
      short8 af[MR], bf[4];
#pragma unroll
      for (int i = 0; i < MR; i++)
        af[i] = *(const short8*)&As[(wm + i * 16 + lm) * KSTEP + kk2 + quad * 8];
#pragma unroll
      for (int i = 0; i < 4; i++)
        bf[i] = *(const short8*)&Bs[(wn + i * 16 + lm) * KSTEP + kk2 + quad * 8];
#pragma unroll
      for (int mi = 0; mi < MR; mi++)
#pragma unroll
        for (int ni = 0; ni < 4; ni++)
          acc[mi][ni] = __builtin_amdgcn_mfma_f32_16x16x32_bf16(
              af[mi], bf[ni], acc[mi][ni], 0, 0, 0);
    }
    __syncthreads();
  }

  ushort* Cseg = (ushort*)C0v;
  int colbase = n0;
  if (SPLIT) {
    int seg = n0 >> 10;
    Cseg = (seg == 0) ? (ushort*)C0v : (seg == 1 ? C1 : C2);
    colbase = n0 & 1023;
  }
#pragma unroll
  for (int mi = 0; mi < MR; mi++) {
#pragma unroll
    for (int ni = 0; ni < 4; ni++) {
      int col = colbase + wn + ni * 16 + lm;
#pragma unroll
      for (int r = 0; r < 4; r++) {
        int row = m0 + wm + mi * 16 + quad * 4 + r;
        size_t ci = (size_t)row * ldc + col;
        float v = acc[mi][ni][r];
        if (EPI == 2 || EPI == 5) v += ext_ld(bias, biasoff + col, isbf);
        if (EPI == 1) v += ext_ld(res, (size_t)row * ldr + col, isbf);
        if (EPI == 5) v += bf2f(((const ushort*)res)[(size_t)row * ldr + col]);
        if (EPI == 2) v = 0.5f * v * (1.0f + erff(v * 0.70710678118654752f));
        if (EPI == 5 && !isbf) ((float*)C0v)[ci] = v;
        else                   Cseg[ci] = f2bf(v);
      }
    }
  }
}

// ---------------- fallback GEMM: B in [K,N] external dtype ------------------
template <int EPI, int FINAL>
__global__ __launch_bounds__(256) void gemm_kn(
    const ushort* __restrict__ A, int lda,
    const void* __restrict__ B, int ldb, size_t boff,
    void* __restrict__ C, int ldc,
    const void* __restrict__ bias, size_t biasoff,
    const void* __restrict__ res, int ldr,
    int M, int K, const uint* __restrict__ flagp) {
  __shared__ __align__(16) ushort As[128 * LDSP];
  __shared__ __align__(16) ushort Bs[128 * LDSP];
  int isbf = (int)*flagp;
  int tid = threadIdx.x;
  int wave = tid >> 6, lane = tid & 63, lm = lane & 15, quad = lane >> 4;
  int m0 = blockIdx.x * 128, n0 = blockIdx.y * 128;
  int wm = (wave >> 1) * 64, wn = (wave & 1) * 64;
  floatx4 acc[4][4] = {};
  int sr = tid >> 2;
  int sc = (tid & 3) * 8;
  int bk = tid >> 4;
  int bn8 = (tid & 15) * 8;

  for (int kk = 0; kk < K; kk += 32) {
    uintx4 va0 = *(const uintx4*)(A + (size_t)(m0 + sr) * lda + kk + sc);
    uintx4 va1 = *(const uintx4*)(A + (size_t)(m0 + sr + 64) * lda + kk + sc);
    *(uintx4*)&As[sr * LDSP + sc] = va0;
    *(uintx4*)&As[(sr + 64) * LDSP + sc] = va1;
    if (isbf) {
      const ushort* Bu = (const ushort*)B;
#pragma unroll
      for (int p = 0; p < 2; p++) {
        int krow = bk + p * 16;
        uintx4 raw = *(const uintx4*)(Bu + boff + (size_t)(kk + krow) * ldb + n0 + bn8);
        ushort tmp[8] __attribute__((aligned(16)));
        *(uintx4*)tmp = raw;
#pragma unroll
        for (int i = 0; i < 8; i++) Bs[(bn8 + i) * LDSP + krow] = san(tmp[i]);
      }
    } else {
      const float* Bf = (const float*)B;
#pragma unroll
      for (int p = 0; p < 2; p++) {
        int krow = bk + p * 16;
        const float* src = Bf + boff + (size_t)(kk + krow) * ldb + n0 + bn8;
        floatx4 f0 = *(const floatx4*)src;
        floatx4 f1 = *(const floatx4*)(src + 4);
#pragma unroll
        for (int i = 0; i < 4; i++) {
          Bs[(bn8 + i) * LDSP + krow] = f2bf(f0[i]);
          Bs[(bn8 + 4 + i) * LDSP + krow] = f2bf(f1[i]);
        }
      }
    }
    __syncthreads();
    short8 af[4], bf[4];
#pragma unroll
    for (int i = 0; i < 4; i++)
      af[i] = *(const short8*)&As[(wm + i * 16 + lm) * LDSP + quad * 8];
#pragma unroll
    for (int i = 0; i < 4; i++)
      bf[i] = *(const short8*)&Bs[(wn + i * 16 + lm) * LDSP + quad * 8];
#pragma unroll
    for (int mi = 0; mi < 4; mi++)
#pragma unroll
      for (int ni = 0; ni < 4; ni++)
        acc[mi][ni] = __builtin_amdgcn_mfma_f32_16x16x32_bf16(
            af[mi], bf[ni], acc[mi][ni], 0, 0, 0);
    __syncthreads();
  }

#pragma unroll
  for (int mi = 0; mi < 4; mi++) {
#pragma unroll
    for (int ni = 0; ni < 4; ni++) {
      int col = n0 + wn + ni * 16 + lm;
#pragma unroll
      for (int r = 0; r < 4; r++) {
        int row = m0 + wm + mi * 16 + quad * 4 + r;
        size_t ci = (size_t)row * ldc + col;
        float v = acc[mi][ni][r];
        if (EPI == 4)
          v += (FINAL && !isbf) ? ((const float*)C)[ci] : bf2f(((const ushort*)C)[ci]);
        if (EPI == 2 || EPI == 4) v += ext_ld(bias, biasoff + col, isbf);
        if (EPI == 1) v += ext_ld(res, (size_t)row * ldr + col, isbf);
        if (EPI == 4) v += bf2f(((const ushort*)res)[(size_t)row * ldr + col]);
        if (EPI == 2) v = 0.5f * v * (1.0f + erff(v * 0.70710678118654752f));
        if (FINAL && !isbf) ((float*)C)[ci] = v;
        else                ((ushort*)C)[ci] = f2bf(v);
      }
    }
  }
}

// ---------------- causal flash attention -----------------------------------
// r13 structure (uniform pairing, swapped softmax, single Vst, 2x
// barrier_lds_only per tile) + r14 VALU trims: (a) Q pre-scaled by 0.125 via
// exact bf16 exponent decrement -> no per-tile scale mults; (b) causal mask
// hoisted on the wave-uniform `full` flag -> 32/33 tiles run mask-free.
__global__ __launch_bounds__(256) void attn_kernel(
    const ushort* __restrict__ q, const ushort* __restrict__ k,
    const ushort* __restrict__ v, ushort* __restrict__ ctx) {
  int tid = threadIdx.x, wave = tid >> 6, lane = tid & 63;
  int lm = lane & 15, quad = lane >> 4;
  int bx = blockIdx.x, h = blockIdx.y, b = blockIdx.z;
  size_t base = (size_t)b * T_SEQ * D_MODEL + h * 64;

  __shared__ __align__(16) ushort Vst[64 * VP];      // [hd][key]
  __shared__ __align__(16) ushort PlAll[4][16 * PP]; // per-wave P
  ushort* Pl = PlAll[wave];

  int vr_r = tid & 63, vcg = (tid >> 6) * 16;
  const ushort* vrow = v + base + vcg;

#pragma unroll
  for (int qsel = 0; qsel < 2; ++qsel) {
    int qt = qsel ? (31 - bx) : bx;
    int qw = qt * 64 + wave * 16;

    short8 aq0 = qscale8(*(const short8*)&q[base + (size_t)(qw + lm) * D_MODEL + quad * 8]);
    short8 aq1 = qscale8(*(const short8*)&q[base + (size_t)(qw + lm) * D_MODEL + 32 + quad * 8]);

    floatx4 O[4] = {};
    float mrq = NEG_BIG, lrq = 0.f;  // running max/denom for query qw+lm

    int ntiles = qt + 1;

    // prefetch tile 0
    uintx4 vv0 = *(const uintx4*)(vrow + (size_t)vr_r * D_MODEL);
    uintx4 vv1 = *(const uintx4*)(vrow + (size_t)vr_r * D_MODEL + 8);
    short8 kfa[4], kfb[4];
#pragma unroll
    for (int g = 0; g < 4; g++) {
      const ushort* kr = &k[base + (size_t)(g * 16 + lm) * D_MODEL + quad * 8];
      kfa[g] = *(const short8*)kr;
      kfb[g] = *(const short8*)(kr + 32);
    }

    for (int kt = 0; kt < ntiles; ++kt) {
      int k0 = kt * 64;
      // scatter prefetched V into shared Vst (all 256 threads)
      {
        ushort t0[8] __attribute__((aligned(16)));
        ushort t1[8] __attribute__((aligned(16)));
        *(uintx4*)t0 = vv0;
        *(uintx4*)t1 = vv1;
#pragma unroll
        for (int i = 0; i < 8; i++) {
          Vst[(vcg + i) * VP + vr_r] = t0[i];
          Vst[(vcg + 8 + i) * VP + vr_r] = t1[i];
        }
      }
      // QK^T SWAPPED: sc[g] = S^T[key=g*16+quad*4+r][query=lm] (pre-scaled)
      floatx4 sc[4];
#pragma unroll
      for (int g = 0; g < 4; g++) {
        floatx4 z = {};
        sc[g] = __builtin_amdgcn_mfma_f32_16x16x32_bf16(kfa[g], aq0, z, 0, 0, 0);
        sc[g] = __builtin_amdgcn_mfma_f32_16x16x32_bf16(kfb[g], aq1, sc[g], 0, 0, 0);
      }
      // issue prefetch for next tile (stays in flight across barriers)
      int k0n = (kt + 1 < ntiles) ? k0 + 64 : k0;
      uintx4 nv0 = *(const uintx4*)(vrow + (size_t)(k0n + vr_r) * D_MODEL);
      uintx4 nv1 = *(const uintx4*)(vrow + (size_t)(k0n + vr_r) * D_MODEL + 8);
      short8 nka[4], nkb[4];
#pragma unroll
      for (int g = 0; g < 4; g++) {
        const ushort* kr = &k[base + (size_t)(k0n + g * 16 + lm) * D_MODEL + quad * 8];
        nka[g] = *(const short8*)kr;
        nkb[g] = *(const short8*)(kr + 32);
      }
      // online softmax: lane owns query qw+lm, 16 keys in-lane.
      // Mask branch hoisted: `full` is wave-uniform; only the diagonal tile
      // (kt==qt) takes the masked path.
      bool full = (k0 + 63 <= qw);
      float a[16];
      if (full) {
#pragma unroll
        for (int g = 0; g < 4; g++)
#pragma unroll
          for (int r = 0; r < 4; r++) a[g * 4 + r] = sc[g][r];
      } else {
        int qrow = qw + lm;
#pragma unroll
        for (int g = 0; g < 4; g++)
#pragma unroll
          for (int r = 0; r < 4; r++) {
            float s = sc[g][r];
            if (k0 + g * 16 + quad * 4 + r > qrow) s = NEG_BIG;
            a[g * 4 + r] = s;
          }
      }
      float m0 = fmaxf(fmaxf(a[0], a[1]), fmaxf(a[2], a[3]));
      float m1 = fmaxf(fmaxf(a[4], a[5]), fmaxf(a[6], a[7]));
      float m2 = fmaxf(fmaxf(a[8], a[9]), fmaxf(a[10], a[11]));
      float m3 = fmaxf(fmaxf(a[12], a[13]), fmaxf(a[14], a[15]));
      float tm = fmaxf(fmaxf(m0, m1), fmaxf(m2, m3));
      tm = fmaxf(tm, __shfl_xor(tm, 16, 64));
      tm = fmaxf(tm, __shfl_xor(tm, 32, 64));
      float mn = fmaxf(mrq, tm);
      float alpha = __expf(mrq - mn);
      float rs0 = 0.f, rs1 = 0.f;
#pragma unroll
      for (int i = 0; i < 8; i++) { a[i] = __expf(a[i] - mn); rs0 += a[i]; }
#pragma unroll
      for (int i = 8; i < 16; i++) { a[i] = __expf(a[i] - mn); rs1 += a[i]; }
      float rsum = rs0 + rs1;
      rsum += __shfl_xor(rsum, 16, 64);
      rsum += __shfl_xor(rsum, 32, 64);
      mrq = mn;
      lrq = lrq * alpha + rsum;
      // rescale O rows (row q = quad*4+r needs alpha of lane lm=quad*4+r)
#pragma unroll
      for (int r = 0; r < 4; r++) {
        float aw = __shfl(alpha, quad * 4 + r, 64);
        O[0][r] *= aw; O[1][r] *= aw; O[2][r] *= aw; O[3][r] *= aw;
      }
      // P write: lane's 4 consecutive keys per g -> one ds_write_b64
#pragma unroll
      for (int g = 0; g < 4; g++) {
        ushort o4[4] __attribute__((aligned(8)));
#pragma unroll
        for (int r = 0; r < 4; r++) o4[r] = f2bf(a[g * 4 + r]);
        *(uint2*)&Pl[lm * PP + g * 16 + quad * 4] = *(uint2*)o4;
      }
      barrier_lds_only();   // Vst scatter + P stores visible; vmem in flight
      short8 pa0 = *(const short8*)&Pl[lm * PP + quad * 8];
      short8 pa1 = *(const short8*)&Pl[lm * PP + 32 + quad * 8];
#pragma unroll
      for (int d4 = 0; d4 < 4; d4++) {
        short8 bv0 = *(const short8*)&Vst[(d4 * 16 + lm) * VP + quad * 8];
        short8 bv1 = *(const short8*)&Vst[(d4 * 16 + lm) * VP + 32 + quad * 8];
        O[d4] = __builtin_amdgcn_mfma_f32_16x16x32_bf16(pa0, bv0, O[d4], 0, 0, 0);
        O[d4] = __builtin_amdgcn_mfma_f32_16x16x32_bf16(pa1, bv1, O[d4], 0, 0, 0);
      }
      barrier_lds_only();   // all waves' Vst/Pl reads drained (lgkm) -> WAR safe
      vv0 = nv0; vv1 = nv1;
#pragma unroll
      for (int g = 0; g < 4; g++) { kfa[g] = nka[g]; kfb[g] = nkb[g]; }
    }
    float linv = 1.0f / fmaxf(lrq, 1e-20f);
#pragma unroll
    for (int r = 0; r < 4; r++) {
      float lw = __shfl(linv, quad * 4 + r, 64);
#pragma unroll
      for (int d4 = 0; d4 < 4; d4++) {
        ctx[base + (size_t)(qw + quad * 4 + r) * D_MODEL + d4 * 16 + lm] =
            f2bf(O[d4][r] * lw);
      }
    }
  }
}

// ---------------------------------------------------------------------------
extern "C" void kernel_launch(void* const* d_in, const int* in_sizes, int n_in,
                              void* d_out, int out_size, void* d_ws, size_t ws_size,
                              hipStream_t stream) {
  const void* x     = d_in[0];
  const void* ln1_g = d_in[1];
  const void* ln1_b = d_in[2];
  const void* Wq    = d_in[3];
  const void* Wk    = d_in[4];
  const void* Wv    = d_in[5];
  const void* Wo    = d_in[6];
  const void* ln2_g = d_in[7];
  const void* ln2_b = d_in[8];
  const void* W1    = d_in[9];
  const void* b1    = d_in[10];
  const void* W2    = d_in[11];
  const void* b2    = d_in[12];

  const int M = 2 * T_SEQ;  // 4096
  const size_t MEG = 1024 * 1024;
  ushort* W = (ushort*)d_ws;
  ushort* Abuf = W;             // h1 -> ctx -> h2
  ushort* kbuf = W + 4 * MEG;   // k -> x2
  ushort* vbuf = W + 8 * MEG;   // v row-major
  ushort* qbuf = (ushort*)d_out;

  dim3 blk(256);
  dim3 g18(32, 8);
  dim3 attng(T_SEQ / 128, N_HEAD, 2);  // 16 q-tile PAIRS x 16 heads x 2 batch

  bool fast = ws_size >= (size_t)40 * MEG + 4096;

  if (fast) {
    ushort* WqkvT = W + 12 * MEG;             // dead after QKV
    ushort* WoT   = W + 15 * MEG;             // dead after Wo
    ushort* W1T   = W + 16 * MEG;
    ushort* W2T   = W + 18 * MEG;
    ushort* act   = W + 8 * MEG;              // [4096,2048] over v/WqkvT/WoT
    uint* flag = (uint*)(W + 20 * MEG);

    detect_dtype<<<1, 256, 0, stream>>>((const ushort*)x, flag);

    // wconv 64x64 tiles (2048 blocks) + LN1 (4096 blocks) in one launch
    prep_all<<<dim3(6144), blk, 0, stream>>>(
        Wq, Wk, Wv, Wo, W1, W2,
        WqkvT, WqkvT + 1 * MEG, WqkvT + 2 * MEG, WoT, W1T, W2T,
        x, ln1_g, ln1_b, Abuf, flag);

    // QKV: 128x128 tile, KSTEP=32 (768 blocks = 3/CU)
    gemm_tt<0, 1, 128, 32><<<dim3(32, 24), blk, 0, stream>>>(
        Abuf, 1024, WqkvT, 1024, qbuf, kbuf, vbuf, 1024,
        nullptr, 0, nullptr, 0, M, 1024, flag);

    attn_kernel<<<attng, blk, 0, stream>>>(qbuf, kbuf, vbuf, Abuf);

    // Wo: 128x64 tile -> 512 blocks = 2/CU
    gemm_tt<1, 0, 64, 32><<<dim3(32, 16), blk, 0, stream>>>(
        Abuf, 1024, WoT, 1024, kbuf, nullptr, nullptr, 1024,
        nullptr, 0, x, 1024, M, 1024, flag);

    ln_kernel<<<dim3(M), blk, 0, stream>>>(kbuf, ln2_g, ln2_b, Abuf, 0, flag);

    // FF1: 128x64 tile -> 1024 blocks = 4/CU (r12: NT=128@2/CU lost 14.5us)
    gemm_tt<2, 0, 64, 32><<<dim3(32, 32), blk, 0, stream>>>(
        Abuf, 1024, W1T, 1024, act, nullptr, nullptr, 2048,
        b1, 0, nullptr, 0, M, 1024, flag);
    // FF2: 128x64 tile -> 512 blocks = 2/CU
    gemm_tt<5, 0, 64, 32><<<dim3(32, 16), blk, 0, stream>>>(
        act, 2048, W2T, 2048, d_out, nullptr, nullptr, 1024,
        b2, 0, kbuf, 1024, M, 2048, flag);
  } else {
    uint* flag = (uint*)(W + 12 * MEG);
    detect_dtype<<<1, 256, 0, stream>>>((const ushort*)x, flag);
    ln_kernel<<<dim3(M), blk, 0, stream>>>(x, ln1_g, ln1_b, Abuf, 1, flag);
    gemm_kn<0, 0><<<g18, blk, 0, stream>>>(Abuf, 1024, Wq, 1024, 0, qbuf, 1024,
                                           nullptr, 0, nullptr, 0, M, 1024, flag);
    gemm_kn<0, 0><<<g18, blk, 0, stream>>>(Abuf, 1024, Wk, 1024, 0, kbuf, 1024,
                                           nullptr, 0, nullptr, 0, M, 1024, flag);
    gemm_kn<0, 0><<<g18, blk, 0, stream>>>(Abuf, 1024, Wv, 1024, 0, vbuf, 1024,
                                           nullptr, 0, nullptr, 0, M, 1024, flag);
    attn_kernel<<<attng, blk, 0, stream>>>(qbuf, kbuf, vbuf, Abuf);
    gemm_kn<1, 0><<<g18, blk, 0, stream>>>(Abuf, 1024, Wo, 1024, 0, kbuf, 1024,
                                           nullptr, 0, x, 1024, M, 1024, flag);
    ln_kernel<<<dim3(M), blk, 0, stream>>>(kbuf, ln2_g, ln2_b, Abuf, 0, flag);
    gemm_kn<2, 0><<<g18, blk, 0, stream>>>(Abuf, 1024, W1, 2048, 0, vbuf, 1024,
                                           b1, 0, nullptr, 0, M, 1024, flag);
    gemm_kn<0, 1><<<g18, blk, 0, stream>>>(vbuf, 1024, W2, 1024, 0, d_out, 1024,
                                           nullptr, 0, nullptr, 0, M, 1024, flag);
    gemm_kn<2, 0><<<g18, blk, 0, stream>>>(Abuf, 1024, W1, 2048, 1024, vbuf, 1024,
                                           b1, 1024, nullptr, 0, M, 1024, flag);
    gemm_kn<4, 1><<<g18, blk, 0, stream>>>(vbuf, 1024, W2, 1024, (size_t)1024 * 1024,
                                           d_out, 1024, b2, 0, kbuf, 1024, M, 1024, flag);
  }
}

// Round 15
// 344.854 us; speedup vs baseline: 1.0636x; 1.0016x over previous
//
#include <hip/hip_runtime.h>
#include <hip/hip_bf16.h>

typedef __attribute__((ext_vector_type(8))) short short8;
typedef __attribute__((ext_vector_type(4))) float floatx4;
typedef __attribute__((ext_vector_type(4))) unsigned int uintx4;

#define D_MODEL 1024
#define T_SEQ   2048
#define N_HEAD  16
#define NEG_BIG (-1e30f)
#define LDSP 40 // fallback-gemm pitch
#define VP 72   // V-tile pitch: 144B rows, 16B-aligned -> true ds_read_b128
#define PP 72   // P-tile pitch
#define RESCALE_THR 8.0f  // T13 defer-max threshold (P bounded by e^8)

static __device__ __forceinline__ float bf2f(ushort u) {
  unsigned int x = ((unsigned int)u) << 16;
  return __builtin_bit_cast(float, x);
}
static __device__ __forceinline__ ushort san(ushort u) {
  return ((u & 0x7F80u) == 0x7F80u) ? (ushort)0 : u;
}
static __device__ __forceinline__ float bf2f_s(ushort u) { return bf2f(san(u)); }
static __device__ __forceinline__ ushort f2bf(float f) {
  unsigned int x = __builtin_bit_cast(unsigned int, f);
  x += 0x7FFFu + ((x >> 16) & 1u);
  return (ushort)(x >> 16);
}
static __device__ __forceinline__ float ext_ld(const void* p, size_t i, int isbf) {
  return isbf ? bf2f_s(((const ushort*)p)[i]) : ((const float*)p)[i];
}
// exact bf16 *0.125: decrement exponent by 3 (power-of-2 -> lossless).
// Guard: tiny/zero exponents flush to signed zero (|x|<2^-123, negligible).
static __device__ __forceinline__ short8 qscale8(short8 v) {
  short8 o;
#pragma unroll
  for (int i = 0; i < 8; i++) {
    ushort u = (ushort)v[i];
    int e = (u >> 7) & 0xFF;
    o[i] = (short)((e > 3) ? (ushort)(u - (3 << 7)) : (ushort)(u & 0x8000u));
  }
  return o;
}
// async global->LDS DMA, 16 B/lane; LDS dest = wave-uniform base + lane*16
static __device__ __forceinline__ void gload16(const void* g, void* l) {
  __builtin_amdgcn_global_load_lds(
      (const __attribute__((address_space(1))) void*)g,
      (__attribute__((address_space(3))) void*)l, 16, 0, 0);
}
// block barrier WITHOUT vmcnt drain: LDS writes visible (lgkmcnt), but
// register-destined global prefetches stay in flight across the barrier.
// r12: attn 99.3->98.0us vs __syncthreads. sched_barrier pins against
// hipcc hoisting past inline-asm waitcnt (rule #18).
static __device__ __forceinline__ void barrier_lds_only() {
  asm volatile("s_waitcnt lgkmcnt(0)" ::: "memory");
  __builtin_amdgcn_s_barrier();
  __builtin_amdgcn_sched_barrier(0);
}

// dtype probe: low ushort of dword -> bf16 data has exp in [0x60,0x8F] ~100%
__global__ void detect_dtype(const ushort* x, uint* flag) {
  int tid = threadIdx.x;
  int cnt = 0;
  for (int j = 0; j < 16; j++) {
    ushort u = x[2 * (tid * 16 + j)];
    int e = (u >> 7) & 0xFF;
    if (e >= 0x60 && e <= 0x8F) cnt++;
  }
  for (int d = 32; d; d >>= 1) cnt += __shfl_xor(cnt, d, 64);
  __shared__ int c[4];
  if ((tid & 63) == 0) c[tid >> 6] = cnt;
  __syncthreads();
  if (tid == 0) flag[0] = (c[0] + c[1] + c[2] + c[3] >= 2048) ? 1u : 0u;
}

// prep_all: weight convert+transpose in 64x64 tiles + LN1 rows.
// Blocks: 0..1023 Wq/Wk/Wv/Wo, 1024..1535 W1, 1536..2047 W2, 2048..6143 LN1.
__global__ __launch_bounds__(256) void prep_all(
    const void* __restrict__ Wq, const void* __restrict__ Wk,
    const void* __restrict__ Wv, const void* __restrict__ Wo,
    const void* __restrict__ W1, const void* __restrict__ W2,
    ushort* __restrict__ oq, ushort* __restrict__ ok, ushort* __restrict__ ov,
    ushort* __restrict__ oo, ushort* __restrict__ o1, ushort* __restrict__ o2,
    const void* __restrict__ x, const void* __restrict__ ln_g,
    const void* __restrict__ ln_b, ushort* __restrict__ ln_out,
    const uint* __restrict__ flagp) {
  int isbf = (int)*flagp;
  int id = blockIdx.x;
  int tid = threadIdx.x;

  if (id >= 2048) {
    // ---- LN1 row (ext input: dtype follows flag) ----
    int row = id - 2048;
    size_t ro = (size_t)row * D_MODEL;
    float v[4], gv[4], bv[4];
    if (!isbf) {
      floatx4 xv = *((const floatx4*)((const float*)x + ro) + tid);
#pragma unroll
      for (int i = 0; i < 4; i++) v[i] = xv[i];
    } else {
#pragma unroll
      for (int i = 0; i < 4; i++) v[i] = bf2f_s(((const ushort*)x)[ro + tid * 4 + i]);
    }
    float s = 0.f, sq = 0.f;
#pragma unroll
    for (int i = 0; i < 4; i++) { s += v[i]; sq += v[i] * v[i]; }
#pragma unroll
    for (int d = 32; d; d >>= 1) {
      s += __shfl_xor(s, d, 64);
      sq += __shfl_xor(sq, d, 64);
    }
    __shared__ float red[8];
    int wave = tid >> 6, lane = tid & 63;
    if (lane == 0) { red[wave] = s; red[4 + wave] = sq; }
    __syncthreads();
    s = red[0] + red[1] + red[2] + red[3];
    sq = red[4] + red[5] + red[6] + red[7];
    float mu = s * (1.0f / D_MODEL);
    float var = sq * (1.0f / D_MODEL) - mu * mu;
    float rs = rsqrtf(fmaxf(var, 0.f) + 1e-5f);
    if (!isbf) {
      floatx4 g4 = *((const floatx4*)ln_g + tid);
      floatx4 b4 = *((const floatx4*)ln_b + tid);
#pragma unroll
      for (int i = 0; i < 4; i++) { gv[i] = g4[i]; bv[i] = b4[i]; }
    } else {
#pragma unroll
      for (int i = 0; i < 4; i++) {
        gv[i] = bf2f_s(((const ushort*)ln_g)[tid * 4 + i]);
        bv[i] = bf2f_s(((const ushort*)ln_b)[tid * 4 + i]);
      }
    }
    ushort o4[4];
#pragma unroll
    for (int i = 0; i < 4; i++) o4[i] = f2bf((v[i] - mu) * rs * gv[i] + bv[i]);
    *(uint2*)(ln_out + ro + tid * 4) = *(uint2*)o4;
    return;
  }

  // ---- weight convert+transpose tile (64x64) ----
  const void* in;
  ushort* out;
  int R, C, local;
  if (id < 1024) {
    int w = id >> 8;
    local = id & 255;
    R = 1024; C = 1024;
    in  = (w == 0) ? Wq : (w == 1) ? Wk : (w == 2) ? Wv : Wo;
    out = (w == 0) ? oq : (w == 1) ? ok : (w == 2) ? ov : oo;
  } else if (id < 1536) {
    local = id - 1024; R = 1024; C = 2048; in = W1; out = o1;
  } else {
    local = id - 1536; R = 2048; C = 1024; in = W2; out = o2;
  }
  int cb = C >> 6;
  int c0 = (local % cb) * 64, r0 = (local / cb) * 64;
  __shared__ float t[64][65];
  int cc = tid & 63, ty = tid >> 6;
  for (int rr = ty; rr < 64; rr += 4)
    t[rr][cc] = ext_ld(in, (size_t)(r0 + rr) * C + c0 + cc, isbf);
  __syncthreads();
  for (int i = ty; i < 64; i += 4)
    out[(size_t)(c0 + i) * R + r0 + cc] = f2bf(t[cc][i]);
}

// ---------------- LayerNorm -> bf16 (LN2 only now) ----------------
__global__ __launch_bounds__(256) void ln_kernel(
    const void* __restrict__ x, const void* __restrict__ g,
    const void* __restrict__ bb, ushort* __restrict__ out,
    int ext, const uint* __restrict__ flagp) {
  int wbf = (int)*flagp;
  int xbf = ext ? wbf : 1;
  int row = blockIdx.x, tid = threadIdx.x;
  size_t ro = (size_t)row * D_MODEL;
  float v[4], gv[4], bv[4];
  if (!xbf) {
    floatx4 xv = *((const floatx4*)((const float*)x + ro) + tid);
#pragma unroll
    for (int i = 0; i < 4; i++) v[i] = xv[i];
  } else {
#pragma unroll
    for (int i = 0; i < 4; i++) v[i] = bf2f_s(((const ushort*)x)[ro + tid * 4 + i]);
  }
  float s = 0.f, sq = 0.f;
#pragma unroll
  for (int i = 0; i < 4; i++) { s += v[i]; sq += v[i] * v[i]; }
#pragma unroll
  for (int d = 32; d; d >>= 1) {
    s += __shfl_xor(s, d, 64);
    sq += __shfl_xor(sq, d, 64);
  }
  __shared__ float red[8];
  int wave = tid >> 6, lane = tid & 63;
  if (lane == 0) { red[wave] = s; red[4 + wave] = sq; }
  __syncthreads();
  s = red[0] + red[1] + red[2] + red[3];
  sq = red[4] + red[5] + red[6] + red[7];
  float mu = s * (1.0f / D_MODEL);
  float var = sq * (1.0f / D_MODEL) - mu * mu;
  float rs = rsqrtf(fmaxf(var, 0.f) + 1e-5f);
  if (!wbf) {
    floatx4 g4 = *((const floatx4*)g + tid);
    floatx4 b4 = *((const floatx4*)bb + tid);
#pragma unroll
    for (int i = 0; i < 4; i++) { gv[i] = g4[i]; bv[i] = b4[i]; }
  } else {
#pragma unroll
    for (int i = 0; i < 4; i++) {
      gv[i] = bf2f_s(((const ushort*)g)[tid * 4 + i]);
      bv[i] = bf2f_s(((const ushort*)bb)[tid * 4 + i]);
    }
  }
  ushort o4[4];
#pragma unroll
  for (int i = 0; i < 4; i++) o4[i] = f2bf((v[i] - mu) * rs * gv[i] + bv[i]);
  *(uint2*)(out + ro + tid * 4) = *(uint2*)o4;
}

// ---------------- fast GEMM: C = A[M,K] @ Bt[N,K]^T, both bf16 --------------
// EPI: 0 plain bf16 | 1 +res(ext) bf16 | 2 +bias(ext)+GELU bf16 |
//      5 +bias(ext)+res(bf16) -> store FINAL dtype
// NT: QKV=128@3/CU (r10: NT=64@6/CU regressed). Wo/FF1/FF2=64 (r4 proved for
// Wo/FF2; r12 proved FF1 NT=128@2/CU loses ~14.5us to NT=64@4/CU). KSTEP=32.
template <int EPI, int SPLIT, int NT, int KSTEP>
__global__ __launch_bounds__(256) void gemm_tt(
    const ushort* __restrict__ A, int lda,
    const ushort* __restrict__ Bt, int ldbt,
    void* __restrict__ C0v, ushort* __restrict__ C1, ushort* __restrict__ C2,
    int ldc,
    const void* __restrict__ bias, size_t biasoff,
    const void* __restrict__ res, int ldr,
    int M, int K, const uint* __restrict__ flagp) {
  __shared__ __align__(16) ushort As[128 * KSTEP];
  __shared__ __align__(16) ushort Bs[NT * KSTEP];
  int isbf = (int)*flagp;
  int tid = threadIdx.x;
  int wave = tid >> 6, lane = tid & 63, lm = lane & 15, quad = lane >> 4;
  int m0 = blockIdx.x * 128, n0 = blockIdx.y * NT;
  constexpr int MR = (NT == 128) ? 4 : 2;
  constexpr int RPW = 512 / KSTEP;   // rows per wave-DMA
  constexpr int RPC = 4 * RPW;       // rows per gload16 call (4 waves)
  constexpr int LPR = KSTEP / 8;     // lanes per row
  int wm = (NT == 128) ? (wave >> 1) * 64 : wave * 32;
  int wn = (NT == 128) ? (wave & 1) * 64 : 0;
  floatx4 acc[MR][4] = {};
  int srl = lane / LPR;
  int scl = (lane % LPR) * 8;

  for (int kk = 0; kk < K; kk += KSTEP) {
#pragma unroll
    for (int i = 0; i < 128 / RPC; i++)
      gload16(A + (size_t)(m0 + i * RPC + wave * RPW + srl) * lda + kk + scl,
              &As[(i * RPC + wave * RPW) * KSTEP]);
#pragma unroll
    for (int i = 0; i < NT / RPC; i++)
      gload16(Bt + (size_t)(n0 + i * RPC + wave * RPW + srl) * ldbt + kk + scl,
              &Bs[(i * RPC + wave * RPW) * KSTEP]);
    __syncthreads();
#pragma unroll
    for (int kk2 = 0; kk2 < KSTEP; kk2 += 32) {
      short8 af[MR], bf[4];
#pragma unroll
      for (int i = 0; i < MR; i++)
        af[i] = *(const short8*)&As[(wm + i * 16 + lm) * KSTEP + kk2 + quad * 8];
#pragma unroll
      for (int i = 0; i < 4; i++)
        bf[i] = *(const short8*)&Bs[(wn + i * 16 + lm) * KSTEP + kk2 + quad * 8];
#pragma unroll
      for (int mi = 0; mi < MR; mi++)
#pragma unroll
        for (int ni = 0; ni < 4; ni++)
          acc[mi][ni] = __builtin_amdgcn_mfma_f32_16x16x32_bf16(
              af[mi], bf[ni], acc[mi][ni], 0, 0, 0);
    }
    __syncthreads();
  }

  ushort* Cseg = (ushort*)C0v;
  int colbase = n0;
  if (SPLIT) {
    int seg = n0 >> 10;
    Cseg = (seg == 0) ? (ushort*)C0v : (seg == 1 ? C1 : C2);
    colbase = n0 & 1023;
  }
#pragma unroll
  for (int mi = 0; mi < MR; mi++) {
#pragma unroll
    for (int ni = 0; ni < 4; ni++) {
      int col = colbase + wn + ni * 16 + lm;
#pragma unroll
      for (int r = 0; r < 4; r++) {
        int row = m0 + wm + mi * 16 + quad * 4 + r;
        size_t ci = (size_t)row * ldc + col;
        float v = acc[mi][ni][r];
        if (EPI == 2 || EPI == 5) v += ext_ld(bias, biasoff + col, isbf);
        if (EPI == 1) v += ext_ld(res, (size_t)row * ldr + col, isbf);
        if (EPI == 5) v += bf2f(((const ushort*)res)[(size_t)row * ldr + col]);
        if (EPI == 2) v = 0.5f * v * (1.0f + erff(v * 0.70710678118654752f));
        if (EPI == 5 && !isbf) ((float*)C0v)[ci] = v;
        else                   Cseg[ci] = f2bf(v);
      }
    }
  }
}

// ---------------- fallback GEMM: B in [K,N] external dtype ------------------
template <int EPI, int FINAL>
__global__ __launch_bounds__(256) void gemm_kn(
    const ushort* __restrict__ A, int lda,
    const void* __restrict__ B, int ldb, size_t boff,
    void* __restrict__ C, int ldc,
    const void* __restrict__ bias, size_t biasoff,
    const void* __restrict__ res, int ldr,
    int M, int K, const uint* __restrict__ flagp) {
  __shared__ __align__(16) ushort As[128 * LDSP];
  __shared__ __align__(16) ushort Bs[128 * LDSP];
  int isbf = (int)*flagp;
  int tid = threadIdx.x;
  int wave = tid >> 6, lane = tid & 63, lm = lane & 15, quad = lane >> 4;
  int m0 = blockIdx.x * 128, n0 = blockIdx.y * 128;
  int wm = (wave >> 1) * 64, wn = (wave & 1) * 64;
  floatx4 acc[4][4] = {};
  int sr = tid >> 2;
  int sc = (tid & 3) * 8;
  int bk = tid >> 4;
  int bn8 = (tid & 15) * 8;

  for (int kk = 0; kk < K; kk += 32) {
    uintx4 va0 = *(const uintx4*)(A + (size_t)(m0 + sr) * lda + kk + sc);
    uintx4 va1 = *(const uintx4*)(A + (size_t)(m0 + sr + 64) * lda + kk + sc);
    *(uintx4*)&As[sr * LDSP + sc] = va0;
    *(uintx4*)&As[(sr + 64) * LDSP + sc] = va1;
    if (isbf) {
      const ushort* Bu = (const ushort*)B;
#pragma unroll
      for (int p = 0; p < 2; p++) {
        int krow = bk + p * 16;
        uintx4 raw = *(const uintx4*)(Bu + boff + (size_t)(kk + krow) * ldb + n0 + bn8);
        ushort tmp[8] __attribute__((aligned(16)));
        *(uintx4*)tmp = raw;
#pragma unroll
        for (int i = 0; i < 8; i++) Bs[(bn8 + i) * LDSP + krow] = san(tmp[i]);
      }
    } else {
      const float* Bf = (const float*)B;
#pragma unroll
      for (int p = 0; p < 2; p++) {
        int krow = bk + p * 16;
        const float* src = Bf + boff + (size_t)(kk + krow) * ldb + n0 + bn8;
        floatx4 f0 = *(const floatx4*)src;
        floatx4 f1 = *(const floatx4*)(src + 4);
#pragma unroll
        for (int i = 0; i < 4; i++) {
          Bs[(bn8 + i) * LDSP + krow] = f2bf(f0[i]);
          Bs[(bn8 + 4 + i) * LDSP + krow] = f2bf(f1[i]);
        }
      }
    }
    __syncthreads();
    short8 af[4], bf[4];
#pragma unroll
    for (int i = 0; i < 4; i++)
      af[i] = *(const short8*)&As[(wm + i * 16 + lm) * LDSP + quad * 8];
#pragma unroll
    for (int i = 0; i < 4; i++)
      bf[i] = *(const short8*)&Bs[(wn + i * 16 + lm) * LDSP + quad * 8];
#pragma unroll
    for (int mi = 0; mi < 4; mi++)
#pragma unroll
      for (int ni = 0; ni < 4; ni++)
        acc[mi][ni] = __builtin_amdgcn_mfma_f32_16x16x32_bf16(
            af[mi], bf[ni], acc[mi][ni], 0, 0, 0);
    __syncthreads();
  }

#pragma unroll
  for (int mi = 0; mi < 4; mi++) {
#pragma unroll
    for (int ni = 0; ni < 4; ni++) {
      int col = n0 + wn + ni * 16 + lm;
#pragma unroll
      for (int r = 0; r < 4; r++) {
        int row = m0 + wm + mi * 16 + quad * 4 + r;
        size_t ci = (size_t)row * ldc + col;
        float v = acc[mi][ni][r];
        if (EPI == 4)
          v += (FINAL && !isbf) ? ((const float*)C)[ci] : bf2f(((const ushort*)C)[ci]);
        if (EPI == 2 || EPI == 4) v += ext_ld(bias, biasoff + col, isbf);
        if (EPI == 1) v += ext_ld(res, (size_t)row * ldr + col, isbf);
        if (EPI == 4) v += bf2f(((const ushort*)res)[(size_t)row * ldr + col]);
        if (EPI == 2) v = 0.5f * v * (1.0f + erff(v * 0.70710678118654752f));
        if (FINAL && !isbf) ((float*)C)[ci] = v;
        else                ((ushort*)C)[ci] = f2bf(v);
      }
    }
  }
}

// ---------------- causal flash attention -----------------------------------
// r14 structure + T13 defer-max: because mrq is replicated across the 4
// lanes of each query, `__all(in-lane max - mrq <= THR)` implies the true
// per-query max also satisfies it -> on the defer path we skip BOTH the
// 2 dependent cross-quad max shuffles AND the alpha/O-rescale (4 bcast
// shuffles + 16 muls). P bounded by e^8 (bf16-safe), accum in f32.
__global__ __launch_bounds__(256) void attn_kernel(
    const ushort* __restrict__ q, const ushort* __restrict__ k,
    const ushort* __restrict__ v, ushort* __restrict__ ctx) {
  int tid = threadIdx.x, wave = tid >> 6, lane = tid & 63;
  int lm = lane & 15, quad = lane >> 4;
  int bx = blockIdx.x, h = blockIdx.y, b = blockIdx.z;
  size_t base = (size_t)b * T_SEQ * D_MODEL + h * 64;

  __shared__ __align__(16) ushort Vst[64 * VP];      // [hd][key]
  __shared__ __align__(16) ushort PlAll[4][16 * PP]; // per-wave P
  ushort* Pl = PlAll[wave];

  int vr_r = tid & 63, vcg = (tid >> 6) * 16;
  const ushort* vrow = v + base + vcg;

#pragma unroll
  for (int qsel = 0; qsel < 2; ++qsel) {
    int qt = qsel ? (31 - bx) : bx;
    int qw = qt * 64 + wave * 16;

    short8 aq0 = qscale8(*(const short8*)&q[base + (size_t)(qw + lm) * D_MODEL + quad * 8]);
    short8 aq1 = qscale8(*(const short8*)&q[base + (size_t)(qw + lm) * D_MODEL + 32 + quad * 8]);

    floatx4 O[4] = {};
    float mrq = NEG_BIG, lrq = 0.f;  // running max/denom for query qw+lm

    int ntiles = qt + 1;

    // prefetch tile 0
    uintx4 vv0 = *(const uintx4*)(vrow + (size_t)vr_r * D_MODEL);
    uintx4 vv1 = *(const uintx4*)(vrow + (size_t)vr_r * D_MODEL + 8);
    short8 kfa[4], kfb[4];
#pragma unroll
    for (int g = 0; g < 4; g++) {
      const ushort* kr = &k[base + (size_t)(g * 16 + lm) * D_MODEL + quad * 8];
      kfa[g] = *(const short8*)kr;
      kfb[g] = *(const short8*)(kr + 32);
    }

    for (int kt = 0; kt < ntiles; ++kt) {
      int k0 = kt * 64;
      // scatter prefetched V into shared Vst (all 256 threads)
      {
        ushort t0[8] __attribute__((aligned(16)));
        ushort t1[8] __attribute__((aligned(16)));
        *(uintx4*)t0 = vv0;
        *(uintx4*)t1 = vv1;
#pragma unroll
        for (int i = 0; i < 8; i++) {
          Vst[(vcg + i) * VP + vr_r] = t0[i];
          Vst[(vcg + 8 + i) * VP + vr_r] = t1[i];
        }
      }
      // QK^T SWAPPED: sc[g] = S^T[key=g*16+quad*4+r][query=lm] (pre-scaled)
      floatx4 sc[4];
#pragma unroll
      for (int g = 0; g < 4; g++) {
        floatx4 z = {};
        sc[g] = __builtin_amdgcn_mfma_f32_16x16x32_bf16(kfa[g], aq0, z, 0, 0, 0);
        sc[g] = __builtin_amdgcn_mfma_f32_16x16x32_bf16(kfb[g], aq1, sc[g], 0, 0, 0);
      }
      // issue prefetch for next tile (stays in flight across barriers)
      int k0n = (kt + 1 < ntiles) ? k0 + 64 : k0;
      uintx4 nv0 = *(const uintx4*)(vrow + (size_t)(k0n + vr_r) * D_MODEL);
      uintx4 nv1 = *(const uintx4*)(vrow + (size_t)(k0n + vr_r) * D_MODEL + 8);
      short8 nka[4], nkb[4];
#pragma unroll
      for (int g = 0; g < 4; g++) {
        const ushort* kr = &k[base + (size_t)(k0n + g * 16 + lm) * D_MODEL + quad * 8];
        nka[g] = *(const short8*)kr;
        nkb[g] = *(const short8*)(kr + 32);
      }
      // online softmax: lane owns query qw+lm, 16 keys in-lane.
      bool full = (k0 + 63 <= qw);
      float a[16];
      if (full) {
#pragma unroll
        for (int g = 0; g < 4; g++)
#pragma unroll
          for (int r = 0; r < 4; r++) a[g * 4 + r] = sc[g][r];
      } else {
        int qrow = qw + lm;
#pragma unroll
        for (int g = 0; g < 4; g++)
#pragma unroll
          for (int r = 0; r < 4; r++) {
            float s = sc[g][r];
            if (k0 + g * 16 + quad * 4 + r > qrow) s = NEG_BIG;
            a[g * 4 + r] = s;
          }
      }
      float m0 = fmaxf(fmaxf(a[0], a[1]), fmaxf(a[2], a[3]));
      float m1 = fmaxf(fmaxf(a[4], a[5]), fmaxf(a[6], a[7]));
      float m2 = fmaxf(fmaxf(a[8], a[9]), fmaxf(a[10], a[11]));
      float m3 = fmaxf(fmaxf(a[12], a[13]), fmaxf(a[14], a[15]));
      float lmax = fmaxf(fmaxf(m0, m1), fmaxf(m2, m3));
      // T13 defer-max: mrq identical across the 4 lanes of each query, so
      // if every lane's LOCAL max is within THR of its mrq, every query's
      // true max is too -> skip cross-quad max reduce + rescale entirely.
      if (!__all(lmax - mrq <= RESCALE_THR)) {
        float tm = fmaxf(lmax, __shfl_xor(lmax, 16, 64));
        tm = fmaxf(tm, __shfl_xor(tm, 32, 64));
        float mn = fmaxf(mrq, tm);
        float alpha = __expf(mrq - mn);
        mrq = mn;
        lrq *= alpha;
#pragma unroll
        for (int r = 0; r < 4; r++) {
          float aw = __shfl(alpha, quad * 4 + r, 64);
          O[0][r] *= aw; O[1][r] *= aw; O[2][r] *= aw; O[3][r] *= aw;
        }
      }
      float rs0 = 0.f, rs1 = 0.f;
#pragma unroll
      for (int i = 0; i < 8; i++) { a[i] = __expf(a[i] - mrq); rs0 += a[i]; }
#pragma unroll
      for (int i = 8; i < 16; i++) { a[i] = __expf(a[i] - mrq); rs1 += a[i]; }
      float rsum = rs0 + rs1;
      rsum += __shfl_xor(rsum, 16, 64);
      rsum += __shfl_xor(rsum, 32, 64);
      lrq += rsum;
      // P write: lane's 4 consecutive keys per g -> one ds_write_b64
#pragma unroll
      for (int g = 0; g < 4; g++) {
        ushort o4[4] __attribute__((aligned(8)));
#pragma unroll
        for (int r = 0; r < 4; r++) o4[r] = f2bf(a[g * 4 + r]);
        *(uint2*)&Pl[lm * PP + g * 16 + quad * 4] = *(uint2*)o4;
      }
      barrier_lds_only();   // Vst scatter + P stores visible; vmem in flight
      short8 pa0 = *(const short8*)&Pl[lm * PP + quad * 8];
      short8 pa1 = *(const short8*)&Pl[lm * PP + 32 + quad * 8];
#pragma unroll
      for (int d4 = 0; d4 < 4; d4++) {
        short8 bv0 = *(const short8*)&Vst[(d4 * 16 + lm) * VP + quad * 8];
        short8 bv1 = *(const short8*)&Vst[(d4 * 16 + lm) * VP + 32 + quad * 8];
        O[d4] = __builtin_amdgcn_mfma_f32_16x16x32_bf16(pa0, bv0, O[d4], 0, 0, 0);
        O[d4] = __builtin_amdgcn_mfma_f32_16x16x32_bf16(pa1, bv1, O[d4], 0, 0, 0);
      }
      barrier_lds_only();   // all waves' Vst/Pl reads drained (lgkm) -> WAR safe
      vv0 = nv0; vv1 = nv1;
#pragma unroll
      for (int g = 0; g < 4; g++) { kfa[g] = nka[g]; kfb[g] = nkb[g]; }
    }
    float linv = 1.0f / fmaxf(lrq, 1e-20f);
#pragma unroll
    for (int r = 0; r < 4; r++) {
      float lw = __shfl(linv, quad * 4 + r, 64);
#pragma unroll
      for (int d4 = 0; d4 < 4; d4++) {
        ctx[base + (size_t)(qw + quad * 4 + r) * D_MODEL + d4 * 16 + lm] =
            f2bf(O[d4][r] * lw);
      }
    }
  }
}

// ---------------------------------------------------------------------------
extern "C" void kernel_launch(void* const* d_in, const int* in_sizes, int n_in,
                              void* d_out, int out_size, void* d_ws, size_t ws_size,
                              hipStream_t stream) {
  const void* x     = d_in[0];
  const void* ln1_g = d_in[1];
  const void* ln1_b = d_in[2];
  const void* Wq    = d_in[3];
  const void* Wk    = d_in[4];
  const void* Wv    = d_in[5];
  const void* Wo    = d_in[6];
  const void* ln2_g = d_in[7];
  const void* ln2_b = d_in[8];
  const void* W1    = d_in[9];
  const void* b1    = d_in[10];
  const void* W2    = d_in[11];
  const void* b2    = d_in[12];

  const int M = 2 * T_SEQ;  // 4096
  const size_t MEG = 1024 * 1024;
  ushort* W = (ushort*)d_ws;
  ushort* Abuf = W;             // h1 -> ctx -> h2
  ushort* kbuf = W + 4 * MEG;   // k -> x2
  ushort* vbuf = W + 8 * MEG;   // v row-major
  ushort* qbuf = (ushort*)d_out;

  dim3 blk(256);
  dim3 g18(32, 8);
  dim3 attng(T_SEQ / 128, N_HEAD, 2);  // 16 q-tile PAIRS x 16 heads x 2 batch

  bool fast = ws_size >= (size_t)40 * MEG + 4096;

  if (fast) {
    ushort* WqkvT = W + 12 * MEG;             // dead after QKV
    ushort* WoT   = W + 15 * MEG;             // dead after Wo
    ushort* W1T   = W + 16 * MEG;
    ushort* W2T   = W + 18 * MEG;
    ushort* act   = W + 8 * MEG;              // [4096,2048] over v/WqkvT/WoT
    uint* flag = (uint*)(W + 20 * MEG);

    detect_dtype<<<1, 256, 0, stream>>>((const ushort*)x, flag);

    // wconv 64x64 tiles (2048 blocks) + LN1 (4096 blocks) in one launch
    prep_all<<<dim3(6144), blk, 0, stream>>>(
        Wq, Wk, Wv, Wo, W1, W2,
        WqkvT, WqkvT + 1 * MEG, WqkvT + 2 * MEG, WoT, W1T, W2T,
        x, ln1_g, ln1_b, Abuf, flag);

    // QKV: 128x128 tile, KSTEP=32 (768 blocks = 3/CU)
    gemm_tt<0, 1, 128, 32><<<dim3(32, 24), blk, 0, stream>>>(
        Abuf, 1024, WqkvT, 1024, qbuf, kbuf, vbuf, 1024,
        nullptr, 0, nullptr, 0, M, 1024, flag);

    attn_kernel<<<attng, blk, 0, stream>>>(qbuf, kbuf, vbuf, Abuf);

    // Wo: 128x64 tile -> 512 blocks = 2/CU
    gemm_tt<1, 0, 64, 32><<<dim3(32, 16), blk, 0, stream>>>(
        Abuf, 1024, WoT, 1024, kbuf, nullptr, nullptr, 1024,
        nullptr, 0, x, 1024, M, 1024, flag);

    ln_kernel<<<dim3(M), blk, 0, stream>>>(kbuf, ln2_g, ln2_b, Abuf, 0, flag);

    // FF1: 128x64 tile -> 1024 blocks = 4/CU (r12: NT=128@2/CU lost 14.5us)
    gemm_tt<2, 0, 64, 32><<<dim3(32, 32), blk, 0, stream>>>(
        Abuf, 1024, W1T, 1024, act, nullptr, nullptr, 2048,
        b1, 0, nullptr, 0, M, 1024, flag);
    // FF2: 128x64 tile -> 512 blocks = 2/CU
    gemm_tt<5, 0, 64, 32><<<dim3(32, 16), blk, 0, stream>>>(
        act, 2048, W2T, 2048, d_out, nullptr, nullptr, 1024,
        b2, 0, kbuf, 1024, M, 2048, flag);
  } else {
    uint* flag = (uint*)(W + 12 * MEG);
    detect_dtype<<<1, 256, 0, stream>>>((const ushort*)x, flag);
    ln_kernel<<<dim3(M), blk, 0, stream>>>(x, ln1_g, ln1_b, Abuf, 1, flag);
    gemm_kn<0, 0><<<g18, blk, 0, stream>>>(Abuf, 1024, Wq, 1024, 0, qbuf, 1024,
                                           nullptr, 0, nullptr, 0, M, 1024, flag);
    gemm_kn<0, 0><<<g18, blk, 0, stream>>>(Abuf, 1024, Wk, 1024, 0, kbuf, 1024,
                                           nullptr, 0, nullptr, 0, M, 1024, flag);
    gemm_kn<0, 0><<<g18, blk, 0, stream>>>(Abuf, 1024, Wv, 1024, 0, vbuf, 1024,
                                           nullptr, 0, nullptr, 0, M, 1024, flag);
    attn_kernel<<<attng, blk, 0, stream>>>(qbuf, kbuf, vbuf, Abuf);
    gemm_kn<1, 0><<<g18, blk, 0, stream>>>(Abuf, 1024, Wo, 1024, 0, kbuf, 1024,
                                           nullptr, 0, x, 1024, M, 1024, flag);
    ln_kernel<<<dim3(M), blk, 0, stream>>>(kbuf, ln2_g, ln2_b, Abuf, 0, flag);
    gemm_kn<2, 0><<<g18, blk, 0, stream>>>(Abuf, 1024, W1, 2048, 0, vbuf, 1024,
                                           b1, 0, nullptr, 0, M, 1024, flag);
    gemm_kn<0, 1><<<g18, blk, 0, stream>>>(vbuf, 1024, W2, 1024, 0, d_out, 1024,
                                           nullptr, 0, nullptr, 0, M, 1024, flag);
    gemm_kn<2, 0><<<g18, blk, 0, stream>>>(Abuf, 1024, W1, 2048, 1024, vbuf, 1024,
                                           b1, 1024, nullptr, 0, M, 1024, flag);
    gemm_kn<4, 1><<<g18, blk, 0, stream>>>(vbuf, 1024, W2, 1024, (size_t)1024 * 1024,
                                           d_out, 1024, b2, 0, kbuf, 1024, M, 1024, flag);
  }
}